// Round 9
// baseline (2729.976 us; speedup 1.0000x reference)
//
#include <hip/hip_runtime.h>
#include <stdint.h>

// LTC encoder B=256,T=1024,F=64,H=128.
// R17 = R16 + TWO batch rows per WG (grid 128, NT 1024, 16 waves).
// R16 post-mortem: VALU 35 + MFMA 30 = 65% pipe-busy, 2 waves/SIMD ->
// stall-bound (post-barrier ds_read latency + dependent MFMA->tail chain
// with nothing to hide behind). Grid is pinned at 1 WG/CU, so the only way
// to more waves/SIMD is more rows/WG: waves 0-7 = row 2b, waves 8-15 =
// row 2b+1 (independent LDS buffers, identical instruction streams ->
// negligible barrier skew). 4 waves/SIMD: row X's stalls hidden by row Y.
// Per-wave structure unchanged from R16: 8 waves/row, 32 cols/wave via TWO
// 16x16x32 MFMA tiles (A-frags shared, tail merged by one cndmask), f32x4
// accs, single red16 (dup lanes carry hc^2), LN-distributed single-barrier
// math (verified R12-R16). VGPR must stay <=128 for 4 waves/SIMD.

#define B_ 256
#define T_ 1024
#define F_ 64
#define H_ 128
#define EPS_ 1e-5f
#define NT_ 1024

typedef _Float16 h2 __attribute__((ext_vector_type(2)));
typedef _Float16 h8 __attribute__((ext_vector_type(8)));
typedef float f32x4 __attribute__((ext_vector_type(4)));
typedef __fp16  f16v2 __attribute__((ext_vector_type(2)));

__device__ __forceinline__ h2 pkf16(float a, float b) {
  union { f16v2 f; h2 h; } c;
  c.f = __builtin_amdgcn_cvt_pkrtz(a, b);
  return c.h;
}
__device__ __forceinline__ uint32_t as_u32(h2 h) { union { h2 h; uint32_t u; } c; c.h = h; return c.u; }

#if __has_builtin(__builtin_amdgcn_rsqf)
__device__ __forceinline__ float rsq_fast(float x) { return __builtin_amdgcn_rsqf(x); }
#else
__device__ __forceinline__ float rsq_fast(float x) { return rsqrtf(x); }
#endif

// 16-lane sum via DPP row_ror (every lane of each 16-row gets the row sum).
#if __has_builtin(__builtin_amdgcn_update_dpp)
template <int CTRL>
__device__ __forceinline__ float dpp_add(float v) {
  union { float f; int i; } a, b;
  a.f = v;
  b.i = __builtin_amdgcn_update_dpp(0, a.i, CTRL, 0xf, 0xf, true);
  return v + b.f;
}
__device__ __forceinline__ float red16(float v) {
  v = dpp_add<0x128>(v);   // row_ror:8
  v = dpp_add<0x124>(v);   // row_ror:4
  v = dpp_add<0x122>(v);   // row_ror:2
  v = dpp_add<0x121>(v);   // row_ror:1
  return v;
}
#else
__device__ __forceinline__ float red16(float v) {
  v += __shfl_xor(v, 1); v += __shfl_xor(v, 2);
  v += __shfl_xor(v, 4); v += __shfl_xor(v, 8);
  return v;
}
#endif

// pack 8 consecutive fp32 weights into one MFMA half-fragment (4 VGPRs)
__device__ __forceinline__ h8 packfrag(const float* p) {
  float4 a = *(const float4*)p;
  float4 b = *(const float4*)(p + 4);
  union { h2 h[4]; h8 v; } c;
  c.h[0] = pkf16(a.x, a.y); c.h[1] = pkf16(a.z, a.w);
  c.h[2] = pkf16(b.x, b.y); c.h[3] = pkf16(b.z, b.w);
  return c.v;
}
// load 8 fp32 weights, fold LN-gamma into the k-dim, accumulate Sum(w*g)
// (= sum of folded values) and Sum(w*be); return folded frag as f16.
__device__ __forceinline__ h8 packfrag_g(const float* w, const float* gv, const float* bv,
                                         float& dg, float& dbe) {
  float4 a = *(const float4*)w;
  float4 b = *(const float4*)(w + 4);
  float4 ga = *(const float4*)gv;
  float4 gb = *(const float4*)(gv + 4);
  float4 ba = *(const float4*)bv;
  float4 bb = *(const float4*)(bv + 4);
  float w0 = a.x*ga.x, w1 = a.y*ga.y, w2 = a.z*ga.z, w3 = a.w*ga.w;
  float w4 = b.x*gb.x, w5 = b.y*gb.y, w6 = b.z*gb.z, w7 = b.w*gb.w;
  dg  += (w0 + w1) + (w2 + w3) + (w4 + w5) + (w6 + w7);
  dbe += a.x*ba.x + a.y*ba.y + a.z*ba.z + a.w*ba.w
       + b.x*bb.x + b.y*bb.y + b.z*bb.z + b.w*bb.w;
  union { h2 h[4]; h8 v; } c;
  c.h[0] = pkf16(w0, w1); c.h[1] = pkf16(w2, w3);
  c.h[2] = pkf16(w4, w5); c.h[3] = pkf16(w6, w7);
  return c.v;
}
// broadcast A-fragment from packed-f16 LDS (16B per lane-group, conflict-free)
__device__ __forceinline__ h8 ldfrag(const uint32_t* p) {
  union { uint4 u; h8 v; } c;
  c.u = *(const uint4*)p;
  return c.v;
}

__device__ __forceinline__ float tanh_fast(float a) {
  float aa = fabsf(a);
  float e  = __expf(2.f * aa);
  float th = 1.f - 2.f * __builtin_amdgcn_rcpf(e + 1.f);
  return copysignf(th, a);
}
__device__ __forceinline__ float softplus_fast(float x) {
  return (x > 20.f) ? x : __logf(1.f + __expf(x));
}

#define MFMA16(A_, B_, C_) __builtin_amdgcn_mfma_f32_16x16x32_f16(A_, B_, C_, 0, 0, 0)

__global__ void __attribute__((amdgpu_flat_work_group_size(NT_, NT_)))
                __attribute__((amdgpu_waves_per_eu(4, 4)))
ltc_scan(
    const float* __restrict__ x,
    const float* __restrict__ Wh0, const float* __restrict__ bh0,
    const float* __restrict__ Wx0, const float* __restrict__ bx0,
    const float* __restrict__ Wt0, const float* __restrict__ bt0,
    const float* __restrict__ tau0, const float* __restrict__ g0,
    const float* __restrict__ be0,
    const float* __restrict__ Wh1, const float* __restrict__ bh1,
    const float* __restrict__ Wx1, const float* __restrict__ bx1,
    const float* __restrict__ Wt1, const float* __restrict__ bt1,
    const float* __restrict__ tau1, const float* __restrict__ g1,
    const float* __restrict__ be1,
    float* __restrict__ out)
{
  __shared__ __align__(16) uint32_t h0p[2][2][64];  // [row][buf] hc0 packed f16
  __shared__ __align__(16) uint32_t h1p[2][2][64];  // [row][buf] hc1 packed f16
  __shared__ __align__(16) uint32_t x4[2][4][32];   // [row] x[t] packed f16 4-ring
  __shared__ __align__(16) float    part[2][4][4];  // [row] {s0,s2_0,s1,s2_1} 4-ring

  const int tid = threadIdx.x;
  const int wid = tid >> 6;
  const int r   = wid >> 3;         // row within WG (0/1)
  const int w8  = wid & 7;          // wave within row
  const int l   = tid & 63;
  const int g4  = (l >> 4) << 2;    // LDS u32 offset of this dup-group's frag
  const int g8  = (l >> 4) << 3;    // k offset (floats) of this dup-group
  const int row = blockIdx.x * 2 + r;
  const float* xg = x + (size_t)row * (T_ * F_);
  const bool selT1 = (l & 16) != 0; // lanes 16-31 / 48-63 serve tile 1

  if (tid < 256) { ((uint32_t*)h0p)[tid] = 0u; ((uint32_t*)h1p)[tid] = 0u; }
  if (tid < 32)  ((float*)part)[tid] = 0.f;
  if (w8 == 0 && l < 32) {          // stage this row's x[0], x[1]
    float2 a = *(const float2*)(xg + 2 * l);
    float2 c = *(const float2*)(xg + F_ + 2 * l);
    x4[r][0][l] = as_u32(pkf16(a.x, a.y));
    x4[r][1][l] = as_u32(pkf16(c.x, c.y));
  }
  __syncthreads();

  if (w8 < 4) {
    // ========== group A: layer 0, step t = i; cols w8*32 .. w8*32+31 ==========
    const int c0 = w8 * 32 + (l & 15);       // tile-0 col (weight load)
    const int ct = w8 * 32 + (l & 31);       // this lane's tail col
    h8 wh0[4], wh1[4], wx0[2], wx1[2], wt0[2], wt1[2];
    float cg, cb;
    {
      float dg0 = 0.f, db0 = 0.f, dg1 = 0.f, db1 = 0.f;
      const float* p0 = Wh0 + c0 * H_ + g8;
      const float* p1 = Wh0 + (c0 + 16) * H_ + g8;
      #pragma unroll
      for (int m = 0; m < 4; ++m) {
        wh0[m] = packfrag_g(p0 + 32 * m, g0 + g8 + 32 * m, be0 + g8 + 32 * m, dg0, db0);
        wh1[m] = packfrag_g(p1 + 32 * m, g0 + g8 + 32 * m, be0 + g8 + 32 * m, dg1, db1);
      }
      dg0 += __shfl_xor(dg0, 16); dg0 += __shfl_xor(dg0, 32);
      db0 += __shfl_xor(db0, 16); db0 += __shfl_xor(db0, 32);
      dg1 += __shfl_xor(dg1, 16); dg1 += __shfl_xor(dg1, 32);
      db1 += __shfl_xor(db1, 16); db1 += __shfl_xor(db1, 32);
      cg = selT1 ? dg1 : dg0; cb = selT1 ? db1 : db0;
      const float* q0 = Wx0 + c0 * F_ + g8;
      const float* q1 = Wx0 + (c0 + 16) * F_ + g8;
      const float* r0 = Wt0 + c0 * F_ + g8;
      const float* r1 = Wt0 + (c0 + 16) * F_ + g8;
      #pragma unroll
      for (int m = 0; m < 2; ++m) {
        wx0[m] = packfrag(q0 + 32 * m); wx1[m] = packfrag(q1 + 32 * m);
        wt0[m] = packfrag(r0 + 32 * m); wt1[m] = packfrag(r1 + 32 * m);
      }
    }
    const float bhx = bh0[ct] + bx0[ct];
    const float btr = bt0[ct], taub = tau0[ct], gr = g0[ct], ber = be0[ct];
    const int  widx = w8 * 16 + ((l & 31) >> 1);
    const bool wlane = ((l & 33) == 0);      // even col, lower 32
    const bool st = (w8 == 0) && (l < 32);

    float hcp = 0.f;
    float2 xcur;                     // x[i+2], loaded one phase early
    if (st) xcur = *(const float2*)(xg + 2 * F_ + 2 * l);

    #pragma unroll 4
    for (int i = 0; i <= T_; ++i) {
      const float2 stt = *(const float2*)&part[r][(i + 3) & 3][0]; // L0 stats of hc0[i-1]
      if (st) {                      // write x[i+2]; issue load of x[i+3]
        x4[r][(i + 2) & 3][l] = as_u32(pkf16(xcur.x, xcur.y));
        int tn = (i + 3 < T_) ? (i + 3) : (T_ - 1);
        xcur = *(const float2*)(xg + tn * F_ + 2 * l);
      }
      const uint32_t* ub = h0p[r][(i + 1) & 1];    // hc0[i-1]
      const uint32_t* xb = x4[r][i & 3];           // x[i]
      f32x4 aH0 = {0.f,0.f,0.f,0.f}, aH1 = {0.f,0.f,0.f,0.f};
      f32x4 aX0 = {0.f,0.f,0.f,0.f}, aX1 = {0.f,0.f,0.f,0.f};
      f32x4 aT0 = {0.f,0.f,0.f,0.f}, aT1 = {0.f,0.f,0.f,0.f};
      #pragma unroll
      for (int m = 0; m < 4; ++m) {
        h8 af = ldfrag(ub + m * 16 + g4);          // shared by both tiles
        aH0 = MFMA16(af, wh0[m], aH0);
        aH1 = MFMA16(af, wh1[m], aH1);
      }
      #pragma unroll
      for (int m = 0; m < 2; ++m) {
        h8 xf = ldfrag(xb + m * 16 + g4);
        aX0 = MFMA16(xf, wx0[m], aX0);
        aX1 = MFMA16(xf, wx1[m], aX1);
        aT0 = MFMA16(xf, wt0[m], aT0);
        aT1 = MFMA16(xf, wt1[m], aT1);
      }
      float aH = selT1 ? aH1[0] : aH0[0];
      float aX = selT1 ? aX1[0] : aX0[0];
      float aT = selT1 ? aT1[0] : aT0[0];
      float mu = stt.x * (1.f / 128.f);
      float m2 = stt.y * (1.f / 128.f);
      float rstd = rsq_fast(m2 - mu * mu + EPS_);
      float fl = (i > 0) ? 1.f : 0.f;
      float sc = fl * rstd;
      float pa = fmaf(sc, aH, fmaf(-sc * mu, cg, fl * cb)) + aX + bhx;
      float pt = aT + btr;
      float f   = tanh_fast(pa);
      float tau = taub + softplus_fast(pt);
      float hold = fl * fmaf((hcp - mu) * rstd, gr, ber);   // hn0[i-1][ct]
      float hc  = fmaf(f - hold, __builtin_amdgcn_rcpf(tau), hold);
      float hc2 = __shfl_xor(hc, 1);
      if (wlane) h0p[r][i & 1][widx] = as_u32(pkf16(hc, hc2));
      float v = (l & 32) ? hc * hc : hc;           // dup rows carry s2
      v = red16(v); v += __shfl_xor(v, 16);
      if (l == 0)  atomicAdd(&part[r][i & 3][0], v);  // Sum hc
      if (l == 32) atomicAdd(&part[r][i & 3][1], v);  // Sum hc^2
      hcp = hc;
      __syncthreads();                             // the ONE barrier per phase
    }
  } else {
    // ========== group B: layer 1, step t = i-1; cols (w8-4)*32 .. +31 ==========
    const int c0 = (w8 - 4) * 32 + (l & 15);
    const int ct = (w8 - 4) * 32 + (l & 31);
    h8 vh0[4], vh1[4], vx0[4], vx1[4], vt0[4], vt1[4];
    float cAg, cAb, cBg, cBb, cTg, cTb;
    {
      float d1=0.f,d2=0.f,d3=0.f,d4=0.f,d5=0.f,d6=0.f;   // tile 0
      float e1=0.f,e2=0.f,e3=0.f,e4=0.f,e5=0.f,e6=0.f;   // tile 1
      const float* p0 = Wh1 + c0 * H_ + g8;
      const float* p1 = Wh1 + (c0 + 16) * H_ + g8;
      const float* q0 = Wx1 + c0 * H_ + g8;
      const float* q1 = Wx1 + (c0 + 16) * H_ + g8;
      const float* r0 = Wt1 + c0 * H_ + g8;
      const float* r1 = Wt1 + (c0 + 16) * H_ + g8;
      #pragma unroll
      for (int m = 0; m < 4; ++m) {
        vh0[m] = packfrag_g(p0 + 32 * m, g1 + g8 + 32 * m, be1 + g8 + 32 * m, d1, d2);
        vh1[m] = packfrag_g(p1 + 32 * m, g1 + g8 + 32 * m, be1 + g8 + 32 * m, e1, e2);
        vx0[m] = packfrag_g(q0 + 32 * m, g0 + g8 + 32 * m, be0 + g8 + 32 * m, d3, d4);
        vx1[m] = packfrag_g(q1 + 32 * m, g0 + g8 + 32 * m, be0 + g8 + 32 * m, e3, e4);
        vt0[m] = packfrag_g(r0 + 32 * m, g0 + g8 + 32 * m, be0 + g8 + 32 * m, d5, d6);
        vt1[m] = packfrag_g(r1 + 32 * m, g0 + g8 + 32 * m, be0 + g8 + 32 * m, e5, e6);
      }
      d1 += __shfl_xor(d1, 16); d1 += __shfl_xor(d1, 32);
      d2 += __shfl_xor(d2, 16); d2 += __shfl_xor(d2, 32);
      d3 += __shfl_xor(d3, 16); d3 += __shfl_xor(d3, 32);
      d4 += __shfl_xor(d4, 16); d4 += __shfl_xor(d4, 32);
      d5 += __shfl_xor(d5, 16); d5 += __shfl_xor(d5, 32);
      d6 += __shfl_xor(d6, 16); d6 += __shfl_xor(d6, 32);
      e1 += __shfl_xor(e1, 16); e1 += __shfl_xor(e1, 32);
      e2 += __shfl_xor(e2, 16); e2 += __shfl_xor(e2, 32);
      e3 += __shfl_xor(e3, 16); e3 += __shfl_xor(e3, 32);
      e4 += __shfl_xor(e4, 16); e4 += __shfl_xor(e4, 32);
      e5 += __shfl_xor(e5, 16); e5 += __shfl_xor(e5, 32);
      e6 += __shfl_xor(e6, 16); e6 += __shfl_xor(e6, 32);
      cAg = selT1 ? e1 : d1; cAb = selT1 ? e2 : d2;
      cBg = selT1 ? e3 : d3; cBb = selT1 ? e4 : d4;
      cTg = selT1 ? e5 : d5; cTb = selT1 ? e6 : d6;
    }
    const float bhx = bh1[ct] + bx1[ct];
    const float btr = bt1[ct], taub = tau1[ct], gr = g1[ct], ber = be1[ct];
    const int  widx = (w8 - 4) * 16 + ((l & 31) >> 1);
    const bool wlane = ((l & 33) == 0);
    const bool zt = (w8 == 7 && l == 63);          // per-row ring zero-er

    float hcp = 0.f;
    #pragma unroll 2
    for (int i = 0; i <= T_; ++i) {
      const float4 P = *(const float4*)&part[r][(i + 3) & 3][0]; // both layers' stats
      if (zt) *(float4*)&part[r][(i + 2) & 3][0] = make_float4(0.f, 0.f, 0.f, 0.f);
      const uint32_t* u1b = h1p[r][(i + 1) & 1];   // hc1[i-2]
      const uint32_t* u0b = h0p[r][(i + 1) & 1];   // hc0[i-1]
      f32x4 aA0 = {0.f,0.f,0.f,0.f}, aA1 = {0.f,0.f,0.f,0.f};
      f32x4 aB0 = {0.f,0.f,0.f,0.f}, aB1 = {0.f,0.f,0.f,0.f};
      f32x4 aT0 = {0.f,0.f,0.f,0.f}, aT1 = {0.f,0.f,0.f,0.f};
      #pragma unroll
      for (int m = 0; m < 4; ++m) {
        h8 af = ldfrag(u1b + m * 16 + g4);         // shared by both tiles
        aA0 = MFMA16(af, vh0[m], aA0);
        aA1 = MFMA16(af, vh1[m], aA1);
      }
      #pragma unroll
      for (int m = 0; m < 4; ++m) {
        h8 f0 = ldfrag(u0b + m * 16 + g4);
        aB0 = MFMA16(f0, vx0[m], aB0);
        aB1 = MFMA16(f0, vx1[m], aB1);
        aT0 = MFMA16(f0, vt0[m], aT0);
        aT1 = MFMA16(f0, vt1[m], aT1);
      }
      float aA = selT1 ? aA1[0] : aA0[0];
      float aB = selT1 ? aB1[0] : aB0[0];
      float aT = selT1 ? aT1[0] : aT0[0];
      float mu0 = P.x * (1.f / 128.f), m20 = P.y * (1.f / 128.f);
      float mu1 = P.z * (1.f / 128.f), m21 = P.w * (1.f / 128.f);
      float rstd0 = rsq_fast(m20 - mu0 * mu0 + EPS_);
      float rstd1 = rsq_fast(m21 - mu1 * mu1 + EPS_);
      float fl0 = (i > 0) ? 1.f : 0.f;
      float fl1 = (i > 1) ? 1.f : 0.f;
      float sc0 = fl0 * rstd0, sc1 = fl1 * rstd1;
      float pa = fmaf(sc1, aA, fmaf(-sc1 * mu1, cAg, fl1 * cAb))
               + fmaf(sc0, aB, fmaf(-sc0 * mu0, cBg, fl0 * cBb)) + bhx;
      float pt = fmaf(sc0, aT, fmaf(-sc0 * mu0, cTg, fl0 * cTb)) + btr;
      float f   = tanh_fast(pa);
      float tau = taub + softplus_fast(pt);
      float hold = fl1 * fmaf((hcp - mu1) * rstd1, gr, ber);  // hn1[i-2][ct]
      float hc  = fmaf(f - hold, __builtin_amdgcn_rcpf(tau), hold);
      float hc2 = __shfl_xor(hc, 1);
      bool we = (i > 0);
      if (we && wlane) h1p[r][i & 1][widx] = as_u32(pkf16(hc, hc2));
      float v = (l & 32) ? hc * hc : hc;
      v = red16(v); v += __shfl_xor(v, 16);
      if (we && l == 0)  atomicAdd(&part[r][i & 3][2], v);
      if (we && l == 32) atomicAdd(&part[r][i & 3][3], v);
      if (we) hcp = hc;
      __syncthreads();                             // the ONE barrier per phase
    }
    // epilogue: hn1[T-1] from stats published at phase T_ (slot T_&3 = 0)
    {
      float mu1 = part[r][T_ & 3][2] * (1.f / 128.f);
      float m21 = part[r][T_ & 3][3] * (1.f / 128.f);
      float rstd1 = rsq_fast(m21 - mu1 * mu1 + EPS_);
      float hn = fmaf((hcp - mu1) * rstd1, gr, ber);
      if (l < 32) out[row * H_ + ct] = hn;
    }
  }
}

extern "C" void kernel_launch(void* const* d_in, const int* in_sizes, int n_in,
                              void* d_out, int out_size, void* d_ws, size_t ws_size,
                              hipStream_t stream) {
  const float* x    = (const float*)d_in[0];
  const float* Wh0  = (const float*)d_in[1];
  const float* bh0  = (const float*)d_in[2];
  const float* Wx0  = (const float*)d_in[3];
  const float* bx0  = (const float*)d_in[4];
  const float* Wt0  = (const float*)d_in[5];
  const float* bt0  = (const float*)d_in[6];
  const float* tau0 = (const float*)d_in[7];
  const float* g0   = (const float*)d_in[8];
  const float* be0  = (const float*)d_in[9];
  const float* Wh1  = (const float*)d_in[10];
  const float* bh1  = (const float*)d_in[11];
  const float* Wx1  = (const float*)d_in[12];
  const float* bx1  = (const float*)d_in[13];
  const float* Wt1  = (const float*)d_in[14];
  const float* bt1  = (const float*)d_in[15];
  const float* tau1 = (const float*)d_in[16];
  const float* g1   = (const float*)d_in[17];
  const float* be1  = (const float*)d_in[18];
  float* out        = (float*)d_out;

  ltc_scan<<<B_ / 2, NT_, 0, stream>>>(x, Wh0, bh0, Wx0, bx0, Wt0, bt0, tau0, g0, be0,
                                       Wh1, bh1, Wx1, bx1, Wt1, bt1, tau1, g1, be1, out);
}

// Round 10
// 1216.389 us; speedup vs baseline: 2.2443x; 2.2443x over previous
//
#include <hip/hip_runtime.h>
#include <stdint.h>

// LTC encoder B=256,T=1024,F=64,H=128. One WG per batch row, NT=512.
// R18 = R16 + A/B group DECOUPLING (no in-loop __syncthreads).
// R17 post-mortem: 2-rows/WG at NT=1024 forced 64-VGPR split -> 133MB spill.
// Revert to NT=512/128-VGPR. R16's residual 35% stall is barrier lockstep:
// all 8 waves burst ds_reads/MFMAs/tails in phase. But A (layer0) never
// reads B's data -> replace the WG barrier with per-group epoch counters:
// done0[4]/done1[4] (one slot per wave, stored after __threadfence_block);
// consumers spin on min>=target. Rings deepened to 4 (h0p,h1p,p0s,p1s).
//   A step i:  wait min(done0)>=i,   min(done1)>=i-3 (ring reuse)
//   B step j:  wait min(done0)>=j+1, min(done1)>=j
// Window [1,4] -> deadlock-free; 1 WG/CU -> all waves co-resident, spin safe.
// Stats are per-wave slots (consumer sums 4 pairs): LDS atomics + zeroing
// deleted; B's fl0 flag gone (stats0[j] always real in new indexing).
// Per-wave math structure identical to R16 (verified): 8 waves, 32 cols via
// two 16x16x32 tiles, LN-distributed gamma-folded weights, f32x4 accs.

#define B_ 256
#define T_ 1024
#define F_ 64
#define H_ 128
#define EPS_ 1e-5f
#define NT_ 512

typedef _Float16 h2 __attribute__((ext_vector_type(2)));
typedef _Float16 h8 __attribute__((ext_vector_type(8)));
typedef float f32x4 __attribute__((ext_vector_type(4)));
typedef __fp16  f16v2 __attribute__((ext_vector_type(2)));

__device__ __forceinline__ h2 pkf16(float a, float b) {
  union { f16v2 f; h2 h; } c;
  c.f = __builtin_amdgcn_cvt_pkrtz(a, b);
  return c.h;
}
__device__ __forceinline__ uint32_t as_u32(h2 h) { union { h2 h; uint32_t u; } c; c.h = h; return c.u; }

#if __has_builtin(__builtin_amdgcn_rsqf)
__device__ __forceinline__ float rsq_fast(float x) { return __builtin_amdgcn_rsqf(x); }
#else
__device__ __forceinline__ float rsq_fast(float x) { return rsqrtf(x); }
#endif

#if __has_builtin(__builtin_amdgcn_update_dpp)
template <int CTRL>
__device__ __forceinline__ float dpp_add(float v) {
  union { float f; int i; } a, b;
  a.f = v;
  b.i = __builtin_amdgcn_update_dpp(0, a.i, CTRL, 0xf, 0xf, true);
  return v + b.f;
}
__device__ __forceinline__ float red16(float v) {
  v = dpp_add<0x128>(v);   // row_ror:8
  v = dpp_add<0x124>(v);   // row_ror:4
  v = dpp_add<0x122>(v);   // row_ror:2
  v = dpp_add<0x121>(v);   // row_ror:1
  return v;
}
#else
__device__ __forceinline__ float red16(float v) {
  v += __shfl_xor(v, 1); v += __shfl_xor(v, 2);
  v += __shfl_xor(v, 4); v += __shfl_xor(v, 8);
  return v;
}
#endif

// spin until min(a[0..3]) >= tgt (epoch counters; producers store post-fence)
__device__ __forceinline__ void wait4(volatile int* a, int tgt) {
  if (tgt <= 0) return;
  for (;;) {
    int m0 = a[0], m1 = a[1], m2 = a[2], m3 = a[3];
    int m = min(min(m0, m1), min(m2, m3));
    if (m >= tgt) break;
    __builtin_amdgcn_s_sleep(1);
  }
  __threadfence_block();            // acquire: order data reads after spin
}

__device__ __forceinline__ h8 packfrag(const float* p) {
  float4 a = *(const float4*)p;
  float4 b = *(const float4*)(p + 4);
  union { h2 h[4]; h8 v; } c;
  c.h[0] = pkf16(a.x, a.y); c.h[1] = pkf16(a.z, a.w);
  c.h[2] = pkf16(b.x, b.y); c.h[3] = pkf16(b.z, b.w);
  return c.v;
}
__device__ __forceinline__ h8 packfrag_g(const float* w, const float* gv, const float* bv,
                                         float& dg, float& dbe) {
  float4 a = *(const float4*)w;
  float4 b = *(const float4*)(w + 4);
  float4 ga = *(const float4*)gv;
  float4 gb = *(const float4*)(gv + 4);
  float4 ba = *(const float4*)bv;
  float4 bb = *(const float4*)(bv + 4);
  float w0 = a.x*ga.x, w1 = a.y*ga.y, w2 = a.z*ga.z, w3 = a.w*ga.w;
  float w4 = b.x*gb.x, w5 = b.y*gb.y, w6 = b.z*gb.z, w7 = b.w*gb.w;
  dg  += (w0 + w1) + (w2 + w3) + (w4 + w5) + (w6 + w7);
  dbe += a.x*ba.x + a.y*ba.y + a.z*ba.z + a.w*ba.w
       + b.x*bb.x + b.y*bb.y + b.z*bb.z + b.w*bb.w;
  union { h2 h[4]; h8 v; } c;
  c.h[0] = pkf16(w0, w1); c.h[1] = pkf16(w2, w3);
  c.h[2] = pkf16(w4, w5); c.h[3] = pkf16(w6, w7);
  return c.v;
}
__device__ __forceinline__ h8 ldfrag(const uint32_t* p) {
  union { uint4 u; h8 v; } c;
  c.u = *(const uint4*)p;
  return c.v;
}

__device__ __forceinline__ float tanh_fast(float a) {
  float aa = fabsf(a);
  float e  = __expf(2.f * aa);
  float th = 1.f - 2.f * __builtin_amdgcn_rcpf(e + 1.f);
  return copysignf(th, a);
}
__device__ __forceinline__ float softplus_fast(float x) {
  return (x > 20.f) ? x : __logf(1.f + __expf(x));
}

#define MFMA16(A_, B_, C_) __builtin_amdgcn_mfma_f32_16x16x32_f16(A_, B_, C_, 0, 0, 0)

__global__ void __attribute__((amdgpu_flat_work_group_size(NT_, NT_)))
                __attribute__((amdgpu_waves_per_eu(2, 2)))
ltc_scan(
    const float* __restrict__ x,
    const float* __restrict__ Wh0, const float* __restrict__ bh0,
    const float* __restrict__ Wx0, const float* __restrict__ bx0,
    const float* __restrict__ Wt0, const float* __restrict__ bt0,
    const float* __restrict__ tau0, const float* __restrict__ g0,
    const float* __restrict__ be0,
    const float* __restrict__ Wh1, const float* __restrict__ bh1,
    const float* __restrict__ Wx1, const float* __restrict__ bx1,
    const float* __restrict__ Wt1, const float* __restrict__ bt1,
    const float* __restrict__ tau1, const float* __restrict__ g1,
    const float* __restrict__ be1,
    float* __restrict__ out)
{
  __shared__ __align__(16) uint32_t h0p[4][64];   // hc0[i] packed f16, slot i&3
  __shared__ __align__(16) uint32_t h1p[4][64];   // hc1[j] packed f16, slot j&3
  __shared__ __align__(16) uint32_t x4r[4][32];   // x[t] packed f16, 4-ring
  __shared__ __align__(16) float2   p0s[4][4];    // L0 stats: [slot][wave]{s,s2}
  __shared__ __align__(16) float2   p1s[4][4];    // L1 stats
  __shared__ volatile int done0[4];               // A-wave epochs
  __shared__ volatile int done1[4];               // B-wave epochs

  const int tid = threadIdx.x;
  const int wid = tid >> 6;
  const int l   = tid & 63;
  const int g4  = (l >> 4) << 2;    // LDS u32 offset of this dup-group's frag
  const int g8  = (l >> 4) << 3;    // k offset (floats) of this dup-group
  const int b   = blockIdx.x;
  const float* xg = x + (size_t)b * (T_ * F_);
  const bool selT1 = (l & 16) != 0; // lanes 16-31 / 48-63 serve tile 1

  if (tid < 256) { ((uint32_t*)h0p)[tid] = 0u; ((uint32_t*)h1p)[tid] = 0u; }
  if (tid < 32)  { ((float*)p0s)[tid] = 0.f; ((float*)p1s)[tid] = 0.f; }
  if (tid < 4)   { done0[tid] = 0; done1[tid] = 0; }
  if (tid < 32) {                   // stage x[0], x[1]
    float2 a = *(const float2*)(xg + 2 * tid);
    float2 c = *(const float2*)(xg + F_ + 2 * tid);
    x4r[0][tid] = as_u32(pkf16(a.x, a.y));
    x4r[1][tid] = as_u32(pkf16(c.x, c.y));
  }
  __syncthreads();                  // the only WG-wide barrier

  if (wid < 4) {
    // ========== group A: layer 0 step i; cols wid*32 .. wid*32+31 ==========
    const int c0 = wid * 32 + (l & 15);
    const int ct = wid * 32 + (l & 31);
    h8 wh0[4], wh1[4], wx0[2], wx1[2], wt0[2], wt1[2];
    float cg, cb;
    {
      float dg0 = 0.f, db0 = 0.f, dg1 = 0.f, db1 = 0.f;
      const float* p0 = Wh0 + c0 * H_ + g8;
      const float* p1 = Wh0 + (c0 + 16) * H_ + g8;
      #pragma unroll
      for (int m = 0; m < 4; ++m) {
        wh0[m] = packfrag_g(p0 + 32 * m, g0 + g8 + 32 * m, be0 + g8 + 32 * m, dg0, db0);
        wh1[m] = packfrag_g(p1 + 32 * m, g0 + g8 + 32 * m, be0 + g8 + 32 * m, dg1, db1);
      }
      dg0 += __shfl_xor(dg0, 16); dg0 += __shfl_xor(dg0, 32);
      db0 += __shfl_xor(db0, 16); db0 += __shfl_xor(db0, 32);
      dg1 += __shfl_xor(dg1, 16); dg1 += __shfl_xor(dg1, 32);
      db1 += __shfl_xor(db1, 16); db1 += __shfl_xor(db1, 32);
      cg = selT1 ? dg1 : dg0; cb = selT1 ? db1 : db0;
      const float* q0 = Wx0 + c0 * F_ + g8;
      const float* q1 = Wx0 + (c0 + 16) * F_ + g8;
      const float* r0 = Wt0 + c0 * F_ + g8;
      const float* r1 = Wt0 + (c0 + 16) * F_ + g8;
      #pragma unroll
      for (int m = 0; m < 2; ++m) {
        wx0[m] = packfrag(q0 + 32 * m); wx1[m] = packfrag(q1 + 32 * m);
        wt0[m] = packfrag(r0 + 32 * m); wt1[m] = packfrag(r1 + 32 * m);
      }
    }
    const float bhx = bh0[ct] + bx0[ct];
    const float btr = bt0[ct], taub = tau0[ct], gr = g0[ct], ber = be0[ct];
    const int  widx = wid * 16 + ((l & 31) >> 1);
    const bool wlane = ((l & 33) == 0);
    const bool st = (wid == 0) && (l < 32);

    float hcp = 0.f;
    float2 xcur;
    if (st) xcur = *(const float2*)(xg + 2 * F_ + 2 * l);

    for (int i = 0; i < T_; ++i) {
      wait4(done0, i);               // h0[i-1] + stats0[i-1] ready (all A)
      wait4(done1, i - 3);           // B done with slot i&3's old contents
      const float4* sp = (const float4*)&p0s[(i + 3) & 3][0];
      float ss, s2s;
      { float4 sa = sp[0], sb = sp[1];
        ss  = (sa.x + sa.z) + (sb.x + sb.z);
        s2s = (sa.y + sa.w) + (sb.y + sb.w); }
      if (st) {                      // write x[i+2]; issue load of x[i+3]
        x4r[(i + 2) & 3][l] = as_u32(pkf16(xcur.x, xcur.y));
        int tn = (i + 3 < T_) ? (i + 3) : (T_ - 1);
        xcur = *(const float2*)(xg + tn * F_ + 2 * l);
      }
      const uint32_t* ub = h0p[(i + 3) & 3];       // hc0[i-1]
      const uint32_t* xb = x4r[i & 3];             // x[i]
      f32x4 aH0 = {0.f,0.f,0.f,0.f}, aH1 = {0.f,0.f,0.f,0.f};
      f32x4 aX0 = {0.f,0.f,0.f,0.f}, aX1 = {0.f,0.f,0.f,0.f};
      f32x4 aT0 = {0.f,0.f,0.f,0.f}, aT1 = {0.f,0.f,0.f,0.f};
      #pragma unroll
      for (int m = 0; m < 4; ++m) {
        h8 af = ldfrag(ub + m * 16 + g4);
        aH0 = MFMA16(af, wh0[m], aH0);
        aH1 = MFMA16(af, wh1[m], aH1);
      }
      #pragma unroll
      for (int m = 0; m < 2; ++m) {
        h8 xf = ldfrag(xb + m * 16 + g4);
        aX0 = MFMA16(xf, wx0[m], aX0);
        aX1 = MFMA16(xf, wx1[m], aX1);
        aT0 = MFMA16(xf, wt0[m], aT0);
        aT1 = MFMA16(xf, wt1[m], aT1);
      }
      float aH = selT1 ? aH1[0] : aH0[0];
      float aX = selT1 ? aX1[0] : aX0[0];
      float aT = selT1 ? aT1[0] : aT0[0];
      float mu = ss * (1.f / 128.f);
      float m2 = s2s * (1.f / 128.f);
      float rstd = rsq_fast(m2 - mu * mu + EPS_);
      float fl = (i > 0) ? 1.f : 0.f;
      float sc = fl * rstd;
      float pa = fmaf(sc, aH, fmaf(-sc * mu, cg, fl * cb)) + aX + bhx;
      float pt = aT + btr;
      float f   = tanh_fast(pa);
      float tau = taub + softplus_fast(pt);
      float hold = fl * fmaf((hcp - mu) * rstd, gr, ber);   // hn0[i-1][ct]
      float hc  = fmaf(f - hold, __builtin_amdgcn_rcpf(tau), hold);
      float hc2 = __shfl_xor(hc, 1);
      if (wlane) h0p[i & 3][widx] = as_u32(pkf16(hc, hc2));
      float v = (l & 32) ? hc * hc : hc;           // dup rows carry s2
      v = red16(v); v += __shfl_xor(v, 16);
      float v2 = __shfl_down(v, 32);               // lane0: v=s, v2=s2
      if (l == 0) p0s[i & 3][wid] = make_float2(v, v2);
      hcp = hc;
      __threadfence_block();                       // release
      if (l == 0) done0[wid] = i + 1;
    }
  } else {
    // ========== group B: layer 1 step j; cols (wid-4)*32 .. +31 ==========
    const int c0 = (wid - 4) * 32 + (l & 15);
    const int ct = (wid - 4) * 32 + (l & 31);
    h8 vh0[4], vh1[4], vx0[4], vx1[4], vt0[4], vt1[4];
    float cAg, cAb, cBg, cBb, cTg, cTb;
    {
      float d1=0.f,d2=0.f,d3=0.f,d4=0.f,d5=0.f,d6=0.f;   // tile 0
      float e1=0.f,e2=0.f,e3=0.f,e4=0.f,e5=0.f,e6=0.f;   // tile 1
      const float* p0 = Wh1 + c0 * H_ + g8;
      const float* p1 = Wh1 + (c0 + 16) * H_ + g8;
      const float* q0 = Wx1 + c0 * H_ + g8;
      const float* q1 = Wx1 + (c0 + 16) * H_ + g8;
      const float* r0 = Wt1 + c0 * H_ + g8;
      const float* r1 = Wt1 + (c0 + 16) * H_ + g8;
      #pragma unroll
      for (int m = 0; m < 4; ++m) {
        vh0[m] = packfrag_g(p0 + 32 * m, g1 + g8 + 32 * m, be1 + g8 + 32 * m, d1, d2);
        vh1[m] = packfrag_g(p1 + 32 * m, g1 + g8 + 32 * m, be1 + g8 + 32 * m, e1, e2);
        vx0[m] = packfrag_g(q0 + 32 * m, g0 + g8 + 32 * m, be0 + g8 + 32 * m, d3, d4);
        vx1[m] = packfrag_g(q1 + 32 * m, g0 + g8 + 32 * m, be0 + g8 + 32 * m, e3, e4);
        vt0[m] = packfrag_g(r0 + 32 * m, g0 + g8 + 32 * m, be0 + g8 + 32 * m, d5, d6);
        vt1[m] = packfrag_g(r1 + 32 * m, g0 + g8 + 32 * m, be0 + g8 + 32 * m, e5, e6);
      }
      d1 += __shfl_xor(d1, 16); d1 += __shfl_xor(d1, 32);
      d2 += __shfl_xor(d2, 16); d2 += __shfl_xor(d2, 32);
      d3 += __shfl_xor(d3, 16); d3 += __shfl_xor(d3, 32);
      d4 += __shfl_xor(d4, 16); d4 += __shfl_xor(d4, 32);
      d5 += __shfl_xor(d5, 16); d5 += __shfl_xor(d5, 32);
      d6 += __shfl_xor(d6, 16); d6 += __shfl_xor(d6, 32);
      e1 += __shfl_xor(e1, 16); e1 += __shfl_xor(e1, 32);
      e2 += __shfl_xor(e2, 16); e2 += __shfl_xor(e2, 32);
      e3 += __shfl_xor(e3, 16); e3 += __shfl_xor(e3, 32);
      e4 += __shfl_xor(e4, 16); e4 += __shfl_xor(e4, 32);
      e5 += __shfl_xor(e5, 16); e5 += __shfl_xor(e5, 32);
      e6 += __shfl_xor(e6, 16); e6 += __shfl_xor(e6, 32);
      cAg = selT1 ? e1 : d1; cAb = selT1 ? e2 : d2;
      cBg = selT1 ? e3 : d3; cBb = selT1 ? e4 : d4;
      cTg = selT1 ? e5 : d5; cTb = selT1 ? e6 : d6;
    }
    const float bhx = bh1[ct] + bx1[ct];
    const float btr = bt1[ct], taub = tau1[ct], gr = g1[ct], ber = be1[ct];
    const int  widx = (wid - 4) * 16 + ((l & 31) >> 1);
    const bool wlane = ((l & 33) == 0);
    const int  bw = wid - 4;

    float hcp = 0.f;
    for (int j = 0; j < T_; ++j) {
      wait4(done0, j + 1);           // h0[j] + stats0[j] ready
      wait4(done1, j);               // h1[j-1] + stats1[j-1] ready (all B)
      float ss0, s20, ss1, s21;
      { const float4* sp = (const float4*)&p0s[j & 3][0];
        float4 sa = sp[0], sb = sp[1];
        ss0 = (sa.x + sa.z) + (sb.x + sb.z);
        s20 = (sa.y + sa.w) + (sb.y + sb.w); }
      { const float4* sp = (const float4*)&p1s[(j + 3) & 3][0];
        float4 sa = sp[0], sb = sp[1];
        ss1 = (sa.x + sa.z) + (sb.x + sb.z);
        s21 = (sa.y + sa.w) + (sb.y + sb.w); }
      const uint32_t* u1b = h1p[(j + 3) & 3];      // hc1[j-1]
      const uint32_t* u0b = h0p[j & 3];            // hc0[j]
      f32x4 aA0 = {0.f,0.f,0.f,0.f}, aA1 = {0.f,0.f,0.f,0.f};
      f32x4 aB0 = {0.f,0.f,0.f,0.f}, aB1 = {0.f,0.f,0.f,0.f};
      f32x4 aT0 = {0.f,0.f,0.f,0.f}, aT1 = {0.f,0.f,0.f,0.f};
      #pragma unroll
      for (int m = 0; m < 4; ++m) {
        h8 af = ldfrag(u1b + m * 16 + g4);
        aA0 = MFMA16(af, vh0[m], aA0);
        aA1 = MFMA16(af, vh1[m], aA1);
      }
      #pragma unroll
      for (int m = 0; m < 4; ++m) {
        h8 f0 = ldfrag(u0b + m * 16 + g4);
        aB0 = MFMA16(f0, vx0[m], aB0);
        aB1 = MFMA16(f0, vx1[m], aB1);
        aT0 = MFMA16(f0, vt0[m], aT0);
        aT1 = MFMA16(f0, vt1[m], aT1);
      }
      float aA = selT1 ? aA1[0] : aA0[0];
      float aB = selT1 ? aB1[0] : aB0[0];
      float aT = selT1 ? aT1[0] : aT0[0];
      float mu0 = ss0 * (1.f / 128.f), m20 = s20 * (1.f / 128.f);
      float mu1 = ss1 * (1.f / 128.f), m21 = s21 * (1.f / 128.f);
      float rstd0 = rsq_fast(m20 - mu0 * mu0 + EPS_);
      float rstd1 = rsq_fast(m21 - mu1 * mu1 + EPS_);
      float fl1 = (j > 0) ? 1.f : 0.f;
      float sc1 = fl1 * rstd1;
      float pa = fmaf(sc1, aA, fmaf(-sc1 * mu1, cAg, fl1 * cAb))
               + fmaf(rstd0, aB, fmaf(-rstd0 * mu0, cBg, cBb)) + bhx;
      float pt = fmaf(rstd0, aT, fmaf(-rstd0 * mu0, cTg, cTb)) + btr;
      float f   = tanh_fast(pa);
      float tau = taub + softplus_fast(pt);
      float hold = fl1 * fmaf((hcp - mu1) * rstd1, gr, ber);  // hn1[j-1][ct]
      float hc  = fmaf(f - hold, __builtin_amdgcn_rcpf(tau), hold);
      float hc2 = __shfl_xor(hc, 1);
      if (wlane) h1p[j & 3][widx] = as_u32(pkf16(hc, hc2));
      float v = (l & 32) ? hc * hc : hc;
      v = red16(v); v += __shfl_xor(v, 16);
      float v2 = __shfl_down(v, 32);
      if (l == 0) p1s[j & 3][bw] = make_float2(v, v2);
      hcp = hc;
      __threadfence_block();                       // release
      if (l == 0) done1[bw] = j + 1;
    }
    // epilogue: hn1[T-1] = LN(hc1[T-1]) with stats1[T-1] (slot (T_-1)&3 = 3)
    wait4(done1, T_);
    {
      float ss1, s21;
      { const float4* sp = (const float4*)&p1s[(T_ - 1) & 3][0];
        float4 sa = sp[0], sb = sp[1];
        ss1 = (sa.x + sa.z) + (sb.x + sb.z);
        s21 = (sa.y + sa.w) + (sb.y + sb.w); }
      float mu1 = ss1 * (1.f / 128.f);
      float m21 = s21 * (1.f / 128.f);
      float rstd1 = rsq_fast(m21 - mu1 * mu1 + EPS_);
      float hn = fmaf((hcp - mu1) * rstd1, gr, ber);
      if (l < 32) out[b * H_ + ct] = hn;
    }
  }
}

extern "C" void kernel_launch(void* const* d_in, const int* in_sizes, int n_in,
                              void* d_out, int out_size, void* d_ws, size_t ws_size,
                              hipStream_t stream) {
  const float* x    = (const float*)d_in[0];
  const float* Wh0  = (const float*)d_in[1];
  const float* bh0  = (const float*)d_in[2];
  const float* Wx0  = (const float*)d_in[3];
  const float* bx0  = (const float*)d_in[4];
  const float* Wt0  = (const float*)d_in[5];
  const float* bt0  = (const float*)d_in[6];
  const float* tau0 = (const float*)d_in[7];
  const float* g0   = (const float*)d_in[8];
  const float* be0  = (const float*)d_in[9];
  const float* Wh1  = (const float*)d_in[10];
  const float* bh1  = (const float*)d_in[11];
  const float* Wx1  = (const float*)d_in[12];
  const float* bx1  = (const float*)d_in[13];
  const float* Wt1  = (const float*)d_in[14];
  const float* bt1  = (const float*)d_in[15];
  const float* tau1 = (const float*)d_in[16];
  const float* g1   = (const float*)d_in[17];
  const float* be1  = (const float*)d_in[18];
  float* out        = (float*)d_out;

  ltc_scan<<<B_, NT_, 0, stream>>>(x, Wh0, bh0, Wx0, bx0, Wt0, bt0, tau0, g0, be0,
                                   Wh1, bh1, Wx1, bx1, Wt1, bt1, tau1, g1, be1, out);
}

// Round 11
// 1008.877 us; speedup vs baseline: 2.7060x; 1.2057x over previous
//
#include <hip/hip_runtime.h>
#include <stdint.h>

// LTC encoder B=256,T=1024,F=64,H=128. One WG per batch row, NT=512.
// R19 = R16 + raw barrier with counted waits (vmcnt NOT drained).
// R18 post-mortem: spin-sync overhead > barrier cost (1216us, revert).
// R16's real stall (~810cyc/step, 35%): __syncthreads emits
// s_waitcnt vmcnt(0) before s_barrier (HIP semantics), so wave A0's x-
// prefetch global load is drained EVERY step -> ~500-900cy HBM latency on
// A0's barrier arrival, all 8 waves wait. Fix per guide T4/m201: in-loop
// barrier = inline-asm "s_waitcnt lgkmcnt(0); s_barrier" (memory clobber:
// LDS writes drain, nothing reorders across) -- vmcnt stays in flight;
// compiler inserts the vmcnt wait only before xcur's use a step later.
// x prefetch deepened to distance 2 (xc0/xc1) to cover cold-HBM latency.
// Everything else identical to R16 (993us): 8 waves, 32 cols/wave via two
// 16x16x32 MFMA tiles, LN-distributed gamma-folded weights, f32x4 accs,
// single red16 stats, LDS-atomic 4-ring stats, one barrier per step.

#define B_ 256
#define T_ 1024
#define F_ 64
#define H_ 128
#define EPS_ 1e-5f
#define NT_ 512

typedef _Float16 h2 __attribute__((ext_vector_type(2)));
typedef _Float16 h8 __attribute__((ext_vector_type(8)));
typedef float f32x4 __attribute__((ext_vector_type(4)));
typedef __fp16  f16v2 __attribute__((ext_vector_type(2)));

__device__ __forceinline__ h2 pkf16(float a, float b) {
  union { f16v2 f; h2 h; } c;
  c.f = __builtin_amdgcn_cvt_pkrtz(a, b);
  return c.h;
}
__device__ __forceinline__ uint32_t as_u32(h2 h) { union { h2 h; uint32_t u; } c; c.h = h; return c.u; }

// workgroup barrier WITHOUT vmcnt drain: LDS writes complete (lgkmcnt),
// global loads stay in flight across the barrier (the whole point).
__device__ __forceinline__ void wg_barrier() {
  asm volatile("s_waitcnt lgkmcnt(0)\n\ts_barrier" ::: "memory");
}

#if __has_builtin(__builtin_amdgcn_rsqf)
__device__ __forceinline__ float rsq_fast(float x) { return __builtin_amdgcn_rsqf(x); }
#else
__device__ __forceinline__ float rsq_fast(float x) { return rsqrtf(x); }
#endif

// 16-lane sum via DPP row_ror (every lane of each 16-row gets the row sum).
#if __has_builtin(__builtin_amdgcn_update_dpp)
template <int CTRL>
__device__ __forceinline__ float dpp_add(float v) {
  union { float f; int i; } a, b;
  a.f = v;
  b.i = __builtin_amdgcn_update_dpp(0, a.i, CTRL, 0xf, 0xf, true);
  return v + b.f;
}
__device__ __forceinline__ float red16(float v) {
  v = dpp_add<0x128>(v);   // row_ror:8
  v = dpp_add<0x124>(v);   // row_ror:4
  v = dpp_add<0x122>(v);   // row_ror:2
  v = dpp_add<0x121>(v);   // row_ror:1
  return v;
}
#else
__device__ __forceinline__ float red16(float v) {
  v += __shfl_xor(v, 1); v += __shfl_xor(v, 2);
  v += __shfl_xor(v, 4); v += __shfl_xor(v, 8);
  return v;
}
#endif

// pack 8 consecutive fp32 weights into one MFMA half-fragment (4 VGPRs)
__device__ __forceinline__ h8 packfrag(const float* p) {
  float4 a = *(const float4*)p;
  float4 b = *(const float4*)(p + 4);
  union { h2 h[4]; h8 v; } c;
  c.h[0] = pkf16(a.x, a.y); c.h[1] = pkf16(a.z, a.w);
  c.h[2] = pkf16(b.x, b.y); c.h[3] = pkf16(b.z, b.w);
  return c.v;
}
// load 8 fp32 weights, fold LN-gamma into the k-dim, accumulate Sum(w*g)
// (= sum of folded values) and Sum(w*be); return folded frag as f16.
__device__ __forceinline__ h8 packfrag_g(const float* w, const float* gv, const float* bv,
                                         float& dg, float& dbe) {
  float4 a = *(const float4*)w;
  float4 b = *(const float4*)(w + 4);
  float4 ga = *(const float4*)gv;
  float4 gb = *(const float4*)(gv + 4);
  float4 ba = *(const float4*)bv;
  float4 bb = *(const float4*)(bv + 4);
  float w0 = a.x*ga.x, w1 = a.y*ga.y, w2 = a.z*ga.z, w3 = a.w*ga.w;
  float w4 = b.x*gb.x, w5 = b.y*gb.y, w6 = b.z*gb.z, w7 = b.w*gb.w;
  dg  += (w0 + w1) + (w2 + w3) + (w4 + w5) + (w6 + w7);
  dbe += a.x*ba.x + a.y*ba.y + a.z*ba.z + a.w*ba.w
       + b.x*bb.x + b.y*bb.y + b.z*bb.z + b.w*bb.w;
  union { h2 h[4]; h8 v; } c;
  c.h[0] = pkf16(w0, w1); c.h[1] = pkf16(w2, w3);
  c.h[2] = pkf16(w4, w5); c.h[3] = pkf16(w6, w7);
  return c.v;
}
// broadcast A-fragment from packed-f16 LDS (16B per lane-group, conflict-free)
__device__ __forceinline__ h8 ldfrag(const uint32_t* p) {
  union { uint4 u; h8 v; } c;
  c.u = *(const uint4*)p;
  return c.v;
}

__device__ __forceinline__ float tanh_fast(float a) {
  float aa = fabsf(a);
  float e  = __expf(2.f * aa);
  float th = 1.f - 2.f * __builtin_amdgcn_rcpf(e + 1.f);
  return copysignf(th, a);
}
__device__ __forceinline__ float softplus_fast(float x) {
  return (x > 20.f) ? x : __logf(1.f + __expf(x));
}

#define MFMA16(A_, B_, C_) __builtin_amdgcn_mfma_f32_16x16x32_f16(A_, B_, C_, 0, 0, 0)

__global__ void __attribute__((amdgpu_flat_work_group_size(NT_, NT_)))
                __attribute__((amdgpu_waves_per_eu(2, 2)))
ltc_scan(
    const float* __restrict__ x,
    const float* __restrict__ Wh0, const float* __restrict__ bh0,
    const float* __restrict__ Wx0, const float* __restrict__ bx0,
    const float* __restrict__ Wt0, const float* __restrict__ bt0,
    const float* __restrict__ tau0, const float* __restrict__ g0,
    const float* __restrict__ be0,
    const float* __restrict__ Wh1, const float* __restrict__ bh1,
    const float* __restrict__ Wx1, const float* __restrict__ bx1,
    const float* __restrict__ Wt1, const float* __restrict__ bt1,
    const float* __restrict__ tau1, const float* __restrict__ g1,
    const float* __restrict__ be1,
    float* __restrict__ out)
{
  __shared__ __align__(16) uint32_t h0p[2][64];   // hc0 packed f16, dbuf
  __shared__ __align__(16) uint32_t h1p[2][64];   // hc1 packed f16, dbuf
  __shared__ __align__(16) uint32_t x4[4][32];    // x[t] packed f16, 4-ring
  __shared__ __align__(16) float    part[4][4];   // {s_L0,s2_L0,s_L1,s2_L1} 4-ring

  const int tid = threadIdx.x;
  const int wid = tid >> 6;
  const int l   = tid & 63;
  const int g4  = (l >> 4) << 2;    // LDS u32 offset of this dup-group's frag
  const int g8  = (l >> 4) << 3;    // k offset (floats) of this dup-group
  const int b   = blockIdx.x;
  const float* xg = x + (size_t)b * (T_ * F_);
  const bool selT1 = (l & 16) != 0; // lanes 16-31 / 48-63 serve tile 1

  if (tid < 128) { ((uint32_t*)h0p)[tid] = 0u; ((uint32_t*)h1p)[tid] = 0u; }
  if (tid < 16)  ((float*)part)[tid] = 0.f;
  if (tid < 32) {                   // stage x[0], x[1]
    float2 a = *(const float2*)(xg + 2 * tid);
    float2 c = *(const float2*)(xg + F_ + 2 * tid);
    x4[0][tid] = as_u32(pkf16(a.x, a.y));
    x4[1][tid] = as_u32(pkf16(c.x, c.y));
  }
  __syncthreads();                  // one full barrier at start (drains init)

  if (wid < 4) {
    // ========== group A: layer 0, step t = i; cols wid*32 .. wid*32+31 ==========
    const int c0 = wid * 32 + (l & 15);      // tile-0 col (weight load)
    const int ct = wid * 32 + (l & 31);      // this lane's tail col
    h8 wh0[4], wh1[4], wx0[2], wx1[2], wt0[2], wt1[2];
    float cg, cb;
    {
      float dg0 = 0.f, db0 = 0.f, dg1 = 0.f, db1 = 0.f;
      const float* p0 = Wh0 + c0 * H_ + g8;
      const float* p1 = Wh0 + (c0 + 16) * H_ + g8;
      #pragma unroll
      for (int m = 0; m < 4; ++m) {
        wh0[m] = packfrag_g(p0 + 32 * m, g0 + g8 + 32 * m, be0 + g8 + 32 * m, dg0, db0);
        wh1[m] = packfrag_g(p1 + 32 * m, g0 + g8 + 32 * m, be0 + g8 + 32 * m, dg1, db1);
      }
      dg0 += __shfl_xor(dg0, 16); dg0 += __shfl_xor(dg0, 32);
      db0 += __shfl_xor(db0, 16); db0 += __shfl_xor(db0, 32);
      dg1 += __shfl_xor(dg1, 16); dg1 += __shfl_xor(dg1, 32);
      db1 += __shfl_xor(db1, 16); db1 += __shfl_xor(db1, 32);
      cg = selT1 ? dg1 : dg0; cb = selT1 ? db1 : db0;
      const float* q0 = Wx0 + c0 * F_ + g8;
      const float* q1 = Wx0 + (c0 + 16) * F_ + g8;
      const float* r0 = Wt0 + c0 * F_ + g8;
      const float* r1 = Wt0 + (c0 + 16) * F_ + g8;
      #pragma unroll
      for (int m = 0; m < 2; ++m) {
        wx0[m] = packfrag(q0 + 32 * m); wx1[m] = packfrag(q1 + 32 * m);
        wt0[m] = packfrag(r0 + 32 * m); wt1[m] = packfrag(r1 + 32 * m);
      }
    }
    const float bhx = bh0[ct] + bx0[ct];
    const float btr = bt0[ct], taub = tau0[ct], gr = g0[ct], ber = be0[ct];
    const int  widx = wid * 16 + ((l & 31) >> 1);
    const bool wlane = ((l & 33) == 0);      // even col, lower 32
    const bool st = (wid == 0) && (l < 32);

    float hcp = 0.f;
    float2 xc0, xc1;                 // x[i+2], x[i+3]: distance-2 prefetch
    if (st) {
      xc0 = *(const float2*)(xg + 2 * F_ + 2 * l);
      xc1 = *(const float2*)(xg + 3 * F_ + 2 * l);
    }

    #pragma unroll 4
    for (int i = 0; i <= T_; ++i) {
      const float2 stt = *(const float2*)&part[(i + 3) & 3][0];  // L0 stats of hc0[i-1]
      if (st) {                      // write x[i+2]; issue load of x[i+4]
        x4[(i + 2) & 3][l] = as_u32(pkf16(xc0.x, xc0.y));
        xc0 = xc1;
        int tn = (i + 4 < T_) ? (i + 4) : (T_ - 1);
        xc1 = *(const float2*)(xg + tn * F_ + 2 * l);
      }
      const uint32_t* ub = h0p[(i + 1) & 1];       // hc0[i-1]
      const uint32_t* xb = x4[i & 3];              // x[i]
      f32x4 aH0 = {0.f,0.f,0.f,0.f}, aH1 = {0.f,0.f,0.f,0.f};
      f32x4 aX0 = {0.f,0.f,0.f,0.f}, aX1 = {0.f,0.f,0.f,0.f};
      f32x4 aT0 = {0.f,0.f,0.f,0.f}, aT1 = {0.f,0.f,0.f,0.f};
      #pragma unroll
      for (int m = 0; m < 4; ++m) {
        h8 af = ldfrag(ub + m * 16 + g4);          // shared by both tiles
        aH0 = MFMA16(af, wh0[m], aH0);
        aH1 = MFMA16(af, wh1[m], aH1);
      }
      #pragma unroll
      for (int m = 0; m < 2; ++m) {
        h8 xf = ldfrag(xb + m * 16 + g4);
        aX0 = MFMA16(xf, wx0[m], aX0);
        aX1 = MFMA16(xf, wx1[m], aX1);
        aT0 = MFMA16(xf, wt0[m], aT0);
        aT1 = MFMA16(xf, wt1[m], aT1);
      }
      float aH = selT1 ? aH1[0] : aH0[0];
      float aX = selT1 ? aX1[0] : aX0[0];
      float aT = selT1 ? aT1[0] : aT0[0];
      float mu = stt.x * (1.f / 128.f);
      float m2 = stt.y * (1.f / 128.f);
      float rstd = rsq_fast(m2 - mu * mu + EPS_);
      float fl = (i > 0) ? 1.f : 0.f;
      float sc = fl * rstd;
      float pa = fmaf(sc, aH, fmaf(-sc * mu, cg, fl * cb)) + aX + bhx;
      float pt = aT + btr;
      float f   = tanh_fast(pa);
      float tau = taub + softplus_fast(pt);
      float hold = fl * fmaf((hcp - mu) * rstd, gr, ber);   // hn0[i-1][ct]
      float hc  = fmaf(f - hold, __builtin_amdgcn_rcpf(tau), hold);
      float hc2 = __shfl_xor(hc, 1);
      if (wlane) h0p[i & 1][widx] = as_u32(pkf16(hc, hc2));
      float v = (l & 32) ? hc * hc : hc;           // dup rows carry s2
      v = red16(v); v += __shfl_xor(v, 16);
      if (l == 0)  atomicAdd(&part[i & 3][0], v);  // Sum hc
      if (l == 32) atomicAdd(&part[i & 3][1], v);  // Sum hc^2
      hcp = hc;
      wg_barrier();                  // lgkmcnt(0)+s_barrier, vmcnt in flight
    }
  } else {
    // ========== group B: layer 1, step t = i-1; cols (wid-4)*32 .. +31 ==========
    const int c0 = (wid - 4) * 32 + (l & 15);
    const int ct = (wid - 4) * 32 + (l & 31);
    h8 vh0[4], vh1[4], vx0[4], vx1[4], vt0[4], vt1[4];
    float cAg, cAb, cBg, cBb, cTg, cTb;
    {
      float d1=0.f,d2=0.f,d3=0.f,d4=0.f,d5=0.f,d6=0.f;   // tile 0
      float e1=0.f,e2=0.f,e3=0.f,e4=0.f,e5=0.f,e6=0.f;   // tile 1
      const float* p0 = Wh1 + c0 * H_ + g8;
      const float* p1 = Wh1 + (c0 + 16) * H_ + g8;
      const float* q0 = Wx1 + c0 * H_ + g8;
      const float* q1 = Wx1 + (c0 + 16) * H_ + g8;
      const float* r0 = Wt1 + c0 * H_ + g8;
      const float* r1 = Wt1 + (c0 + 16) * H_ + g8;
      #pragma unroll
      for (int m = 0; m < 4; ++m) {
        vh0[m] = packfrag_g(p0 + 32 * m, g1 + g8 + 32 * m, be1 + g8 + 32 * m, d1, d2);
        vh1[m] = packfrag_g(p1 + 32 * m, g1 + g8 + 32 * m, be1 + g8 + 32 * m, e1, e2);
        vx0[m] = packfrag_g(q0 + 32 * m, g0 + g8 + 32 * m, be0 + g8 + 32 * m, d3, d4);
        vx1[m] = packfrag_g(q1 + 32 * m, g0 + g8 + 32 * m, be0 + g8 + 32 * m, e3, e4);
        vt0[m] = packfrag_g(r0 + 32 * m, g0 + g8 + 32 * m, be0 + g8 + 32 * m, d5, d6);
        vt1[m] = packfrag_g(r1 + 32 * m, g0 + g8 + 32 * m, be0 + g8 + 32 * m, e5, e6);
      }
      d1 += __shfl_xor(d1, 16); d1 += __shfl_xor(d1, 32);
      d2 += __shfl_xor(d2, 16); d2 += __shfl_xor(d2, 32);
      d3 += __shfl_xor(d3, 16); d3 += __shfl_xor(d3, 32);
      d4 += __shfl_xor(d4, 16); d4 += __shfl_xor(d4, 32);
      d5 += __shfl_xor(d5, 16); d5 += __shfl_xor(d5, 32);
      d6 += __shfl_xor(d6, 16); d6 += __shfl_xor(d6, 32);
      e1 += __shfl_xor(e1, 16); e1 += __shfl_xor(e1, 32);
      e2 += __shfl_xor(e2, 16); e2 += __shfl_xor(e2, 32);
      e3 += __shfl_xor(e3, 16); e3 += __shfl_xor(e3, 32);
      e4 += __shfl_xor(e4, 16); e4 += __shfl_xor(e4, 32);
      e5 += __shfl_xor(e5, 16); e5 += __shfl_xor(e5, 32);
      e6 += __shfl_xor(e6, 16); e6 += __shfl_xor(e6, 32);
      cAg = selT1 ? e1 : d1; cAb = selT1 ? e2 : d2;
      cBg = selT1 ? e3 : d3; cBb = selT1 ? e4 : d4;
      cTg = selT1 ? e5 : d5; cTb = selT1 ? e6 : d6;
    }
    const float bhx = bh1[ct] + bx1[ct];
    const float btr = bt1[ct], taub = tau1[ct], gr = g1[ct], ber = be1[ct];
    const int  widx = (wid - 4) * 16 + ((l & 31) >> 1);
    const bool wlane = ((l & 33) == 0);
    const bool zt = (tid == NT_ - 1);              // ring zero-er

    float hcp = 0.f;
    #pragma unroll 2
    for (int i = 0; i <= T_; ++i) {
      const float4 P = *(const float4*)&part[(i + 3) & 3][0];  // both layers' stats
      if (zt) *(float4*)&part[(i + 2) & 3][0] = make_float4(0.f, 0.f, 0.f, 0.f);
      const uint32_t* u1b = h1p[(i + 1) & 1];      // hc1[i-2]
      const uint32_t* u0b = h0p[(i + 1) & 1];      // hc0[i-1]
      f32x4 aA0 = {0.f,0.f,0.f,0.f}, aA1 = {0.f,0.f,0.f,0.f};
      f32x4 aB0 = {0.f,0.f,0.f,0.f}, aB1 = {0.f,0.f,0.f,0.f};
      f32x4 aT0 = {0.f,0.f,0.f,0.f}, aT1 = {0.f,0.f,0.f,0.f};
      #pragma unroll
      for (int m = 0; m < 4; ++m) {
        h8 af = ldfrag(u1b + m * 16 + g4);         // shared by both tiles
        aA0 = MFMA16(af, vh0[m], aA0);
        aA1 = MFMA16(af, vh1[m], aA1);
      }
      #pragma unroll
      for (int m = 0; m < 4; ++m) {
        h8 f0 = ldfrag(u0b + m * 16 + g4);
        aB0 = MFMA16(f0, vx0[m], aB0);
        aB1 = MFMA16(f0, vx1[m], aB1);
        aT0 = MFMA16(f0, vt0[m], aT0);
        aT1 = MFMA16(f0, vt1[m], aT1);
      }
      float aA = selT1 ? aA1[0] : aA0[0];
      float aB = selT1 ? aB1[0] : aB0[0];
      float aT = selT1 ? aT1[0] : aT0[0];
      float mu0 = P.x * (1.f / 128.f), m20 = P.y * (1.f / 128.f);
      float mu1 = P.z * (1.f / 128.f), m21 = P.w * (1.f / 128.f);
      float rstd0 = rsq_fast(m20 - mu0 * mu0 + EPS_);
      float rstd1 = rsq_fast(m21 - mu1 * mu1 + EPS_);
      float fl0 = (i > 0) ? 1.f : 0.f;
      float fl1 = (i > 1) ? 1.f : 0.f;
      float sc0 = fl0 * rstd0, sc1 = fl1 * rstd1;
      float pa = fmaf(sc1, aA, fmaf(-sc1 * mu1, cAg, fl1 * cAb))
               + fmaf(sc0, aB, fmaf(-sc0 * mu0, cBg, fl0 * cBb)) + bhx;
      float pt = fmaf(sc0, aT, fmaf(-sc0 * mu0, cTg, fl0 * cTb)) + btr;
      float f   = tanh_fast(pa);
      float tau = taub + softplus_fast(pt);
      float hold = fl1 * fmaf((hcp - mu1) * rstd1, gr, ber);  // hn1[i-2][ct]
      float hc  = fmaf(f - hold, __builtin_amdgcn_rcpf(tau), hold);
      float hc2 = __shfl_xor(hc, 1);
      bool we = (i > 0);
      if (we && wlane) h1p[i & 1][widx] = as_u32(pkf16(hc, hc2));
      float v = (l & 32) ? hc * hc : hc;
      v = red16(v); v += __shfl_xor(v, 16);
      if (we && l == 0)  atomicAdd(&part[i & 3][2], v);
      if (we && l == 32) atomicAdd(&part[i & 3][3], v);
      if (we) hcp = hc;
      wg_barrier();                  // lgkmcnt(0)+s_barrier, vmcnt in flight
    }
    // epilogue: hn1[T-1] from stats published at phase T_ (slot T_&3 = 0)
    {
      float mu1 = part[T_ & 3][2] * (1.f / 128.f);
      float m21 = part[T_ & 3][3] * (1.f / 128.f);
      float rstd1 = rsq_fast(m21 - mu1 * mu1 + EPS_);
      float hn = fmaf((hcp - mu1) * rstd1, gr, ber);
      if (l < 32) out[b * H_ + ct] = hn;
    }
  }
}

extern "C" void kernel_launch(void* const* d_in, const int* in_sizes, int n_in,
                              void* d_out, int out_size, void* d_ws, size_t ws_size,
                              hipStream_t stream) {
  const float* x    = (const float*)d_in[0];
  const float* Wh0  = (const float*)d_in[1];
  const float* bh0  = (const float*)d_in[2];
  const float* Wx0  = (const float*)d_in[3];
  const float* bx0  = (const float*)d_in[4];
  const float* Wt0  = (const float*)d_in[5];
  const float* bt0  = (const float*)d_in[6];
  const float* tau0 = (const float*)d_in[7];
  const float* g0   = (const float*)d_in[8];
  const float* be0  = (const float*)d_in[9];
  const float* Wh1  = (const float*)d_in[10];
  const float* bh1  = (const float*)d_in[11];
  const float* Wx1  = (const float*)d_in[12];
  const float* bx1  = (const float*)d_in[13];
  const float* Wt1  = (const float*)d_in[14];
  const float* bt1  = (const float*)d_in[15];
  const float* tau1 = (const float*)d_in[16];
  const float* g1   = (const float*)d_in[17];
  const float* be1  = (const float*)d_in[18];
  float* out        = (float*)d_out;

  ltc_scan<<<B_, NT_, 0, stream>>>(x, Wh0, bh0, Wx0, bx0, Wt0, bt0, tau0, g0, be0,
                                   Wh1, bh1, Wx1, bx1, Wt1, bt1, tau1, g1, be1, out);
}

// Round 12
// 875.783 us; speedup vs baseline: 3.1172x; 1.1520x over previous
//
#include <hip/hip_runtime.h>
#include <stdint.h>

// LTC encoder B=256,T=1024,F=64,H=128. One WG per batch row, NT=512.
// R20 = R19 + (1) A publishes hn0 (the LN output it computes anyway as
// `hold`); B runs TWO steps behind (j=p-2) and consumes hn0[j] directly ->
// B's Wx1/Wt1 paths need no LN-distribution: stats0 read, mu0/rstd0 (rsq),
// sc0 and 4 fold-FMAs deleted from B's tail; 4 fold constants freed. Also
// re-balances groups (B was the slowest wave at every barrier).
// (2) per-wave-slot stats (float2 store per wave, consumer sums 4 slots):
// kills the 4-deep LDS-atomic chain and ring zeroing.
// (3) 1026 phases; rings audited: hn0p[4] (w@s+1,r@s+2,ow@s+5), h0p[2]
// A-only, h1p[2] B-only, stats[4] per-group.
// R19 post-mortem: vmcnt-drain theory wrong (+1%); stall = recurrence
// chain w/ 2 waves/SIMD; attack = shorten chain + balance waves.
// Base structure (verified R16-R19): 8 waves, 32 cols/wave via two
// 16x16x32 MFMA tiles, gamma-folded self-recurrence weights, f32x4 accs,
// single red16, lgkm-only wg_barrier.

#define B_ 256
#define T_ 1024
#define F_ 64
#define H_ 128
#define EPS_ 1e-5f
#define NT_ 512

typedef _Float16 h2 __attribute__((ext_vector_type(2)));
typedef _Float16 h8 __attribute__((ext_vector_type(8)));
typedef float f32x4 __attribute__((ext_vector_type(4)));
typedef __fp16  f16v2 __attribute__((ext_vector_type(2)));

__device__ __forceinline__ h2 pkf16(float a, float b) {
  union { f16v2 f; h2 h; } c;
  c.f = __builtin_amdgcn_cvt_pkrtz(a, b);
  return c.h;
}
__device__ __forceinline__ uint32_t as_u32(h2 h) { union { h2 h; uint32_t u; } c; c.h = h; return c.u; }

// workgroup barrier WITHOUT vmcnt drain: LDS ops complete (lgkmcnt),
// global loads stay in flight across the barrier.
__device__ __forceinline__ void wg_barrier() {
  asm volatile("s_waitcnt lgkmcnt(0)\n\ts_barrier" ::: "memory");
}

#if __has_builtin(__builtin_amdgcn_rsqf)
__device__ __forceinline__ float rsq_fast(float x) { return __builtin_amdgcn_rsqf(x); }
#else
__device__ __forceinline__ float rsq_fast(float x) { return rsqrtf(x); }
#endif

// 16-lane sum via DPP row_ror (every lane of each 16-row gets the row sum).
#if __has_builtin(__builtin_amdgcn_update_dpp)
template <int CTRL>
__device__ __forceinline__ float dpp_add(float v) {
  union { float f; int i; } a, b;
  a.f = v;
  b.i = __builtin_amdgcn_update_dpp(0, a.i, CTRL, 0xf, 0xf, true);
  return v + b.f;
}
__device__ __forceinline__ float red16(float v) {
  v = dpp_add<0x128>(v);   // row_ror:8
  v = dpp_add<0x124>(v);   // row_ror:4
  v = dpp_add<0x122>(v);   // row_ror:2
  v = dpp_add<0x121>(v);   // row_ror:1
  return v;
}
#else
__device__ __forceinline__ float red16(float v) {
  v += __shfl_xor(v, 1); v += __shfl_xor(v, 2);
  v += __shfl_xor(v, 4); v += __shfl_xor(v, 8);
  return v;
}
#endif

// pack 8 consecutive fp32 weights into one MFMA half-fragment (4 VGPRs)
__device__ __forceinline__ h8 packfrag(const float* p) {
  float4 a = *(const float4*)p;
  float4 b = *(const float4*)(p + 4);
  union { h2 h[4]; h8 v; } c;
  c.h[0] = pkf16(a.x, a.y); c.h[1] = pkf16(a.z, a.w);
  c.h[2] = pkf16(b.x, b.y); c.h[3] = pkf16(b.z, b.w);
  return c.v;
}
// load 8 fp32 weights, fold LN-gamma into the k-dim, accumulate Sum(w*g)
// (= sum of folded values) and Sum(w*be); return folded frag as f16.
__device__ __forceinline__ h8 packfrag_g(const float* w, const float* gv, const float* bv,
                                         float& dg, float& dbe) {
  float4 a = *(const float4*)w;
  float4 b = *(const float4*)(w + 4);
  float4 ga = *(const float4*)gv;
  float4 gb = *(const float4*)(gv + 4);
  float4 ba = *(const float4*)bv;
  float4 bb = *(const float4*)(bv + 4);
  float w0 = a.x*ga.x, w1 = a.y*ga.y, w2 = a.z*ga.z, w3 = a.w*ga.w;
  float w4 = b.x*gb.x, w5 = b.y*gb.y, w6 = b.z*gb.z, w7 = b.w*gb.w;
  dg  += (w0 + w1) + (w2 + w3) + (w4 + w5) + (w6 + w7);
  dbe += a.x*ba.x + a.y*ba.y + a.z*ba.z + a.w*ba.w
       + b.x*bb.x + b.y*bb.y + b.z*bb.z + b.w*bb.w;
  union { h2 h[4]; h8 v; } c;
  c.h[0] = pkf16(w0, w1); c.h[1] = pkf16(w2, w3);
  c.h[2] = pkf16(w4, w5); c.h[3] = pkf16(w6, w7);
  return c.v;
}
// broadcast A-fragment from packed-f16 LDS (16B per lane-group, conflict-free)
__device__ __forceinline__ h8 ldfrag(const uint32_t* p) {
  union { uint4 u; h8 v; } c;
  c.u = *(const uint4*)p;
  return c.v;
}

__device__ __forceinline__ float tanh_fast(float a) {
  float aa = fabsf(a);
  float e  = __expf(2.f * aa);
  float th = 1.f - 2.f * __builtin_amdgcn_rcpf(e + 1.f);
  return copysignf(th, a);
}
__device__ __forceinline__ float softplus_fast(float x) {
  return (x > 20.f) ? x : __logf(1.f + __expf(x));
}

#define MFMA16(A_, B_, C_) __builtin_amdgcn_mfma_f32_16x16x32_f16(A_, B_, C_, 0, 0, 0)

__global__ void __attribute__((amdgpu_flat_work_group_size(NT_, NT_)))
                __attribute__((amdgpu_waves_per_eu(2, 2)))
ltc_scan(
    const float* __restrict__ x,
    const float* __restrict__ Wh0, const float* __restrict__ bh0,
    const float* __restrict__ Wx0, const float* __restrict__ bx0,
    const float* __restrict__ Wt0, const float* __restrict__ bt0,
    const float* __restrict__ tau0, const float* __restrict__ g0,
    const float* __restrict__ be0,
    const float* __restrict__ Wh1, const float* __restrict__ bh1,
    const float* __restrict__ Wx1, const float* __restrict__ bx1,
    const float* __restrict__ Wt1, const float* __restrict__ bt1,
    const float* __restrict__ tau1, const float* __restrict__ g1,
    const float* __restrict__ be1,
    float* __restrict__ out)
{
  __shared__ __align__(16) uint32_t h0p[2][64];   // hc0 raw, A-only dbuf
  __shared__ __align__(16) uint32_t h1p[2][64];   // hc1 raw, B-only dbuf
  __shared__ __align__(16) uint32_t hn0p[4][64];  // hn0[i] = LN(hc0[i]), 4-ring
  __shared__ __align__(16) uint32_t x4[4][32];    // x[t] packed f16, 4-ring
  __shared__ __align__(16) float2   p0s[4][4];    // L0 stats [slot][wave]{s,s2}
  __shared__ __align__(16) float2   p1s[4][4];    // L1 stats

  const int tid = threadIdx.x;
  const int wid = tid >> 6;
  const int l   = tid & 63;
  const int g4  = (l >> 4) << 2;    // LDS u32 offset of this dup-group's frag
  const int g8  = (l >> 4) << 3;    // k offset (floats) of this dup-group
  const int b   = blockIdx.x;
  const float* xg = x + (size_t)b * (T_ * F_);
  const bool selT1 = (l & 16) != 0; // lanes 16-31 / 48-63 serve tile 1

  if (tid < 128) { ((uint32_t*)h0p)[tid] = 0u; ((uint32_t*)h1p)[tid] = 0u; }
  if (tid < 32)  { ((float*)p0s)[tid] = 0.f; ((float*)p1s)[tid] = 0.f; }
  if (tid < 32) {                   // stage x[0], x[1]
    float2 a = *(const float2*)(xg + 2 * tid);
    float2 c = *(const float2*)(xg + F_ + 2 * tid);
    x4[0][tid] = as_u32(pkf16(a.x, a.y));
    x4[1][tid] = as_u32(pkf16(c.x, c.y));
  }
  __syncthreads();                  // one full barrier at start (drains init)

  if (wid < 4) {
    // ========== group A: layer 0, step i = p; cols wid*32 .. +31 ==========
    const int c0 = wid * 32 + (l & 15);
    const int ct = wid * 32 + (l & 31);
    h8 wh0[4], wh1[4], wx0[2], wx1[2], wt0[2], wt1[2];
    float cg, cb;
    {
      float dg0 = 0.f, db0 = 0.f, dg1 = 0.f, db1 = 0.f;
      const float* p0 = Wh0 + c0 * H_ + g8;
      const float* p1 = Wh0 + (c0 + 16) * H_ + g8;
      #pragma unroll
      for (int m = 0; m < 4; ++m) {
        wh0[m] = packfrag_g(p0 + 32 * m, g0 + g8 + 32 * m, be0 + g8 + 32 * m, dg0, db0);
        wh1[m] = packfrag_g(p1 + 32 * m, g0 + g8 + 32 * m, be0 + g8 + 32 * m, dg1, db1);
      }
      dg0 += __shfl_xor(dg0, 16); dg0 += __shfl_xor(dg0, 32);
      db0 += __shfl_xor(db0, 16); db0 += __shfl_xor(db0, 32);
      dg1 += __shfl_xor(dg1, 16); dg1 += __shfl_xor(dg1, 32);
      db1 += __shfl_xor(db1, 16); db1 += __shfl_xor(db1, 32);
      cg = selT1 ? dg1 : dg0; cb = selT1 ? db1 : db0;
      const float* q0 = Wx0 + c0 * F_ + g8;
      const float* q1 = Wx0 + (c0 + 16) * F_ + g8;
      const float* r0 = Wt0 + c0 * F_ + g8;
      const float* r1 = Wt0 + (c0 + 16) * F_ + g8;
      #pragma unroll
      for (int m = 0; m < 2; ++m) {
        wx0[m] = packfrag(q0 + 32 * m); wx1[m] = packfrag(q1 + 32 * m);
        wt0[m] = packfrag(r0 + 32 * m); wt1[m] = packfrag(r1 + 32 * m);
      }
    }
    const float bhx = bh0[ct] + bx0[ct];
    const float btr = bt0[ct], taub = tau0[ct], gr = g0[ct], ber = be0[ct];
    const int  widx = wid * 16 + ((l & 31) >> 1);
    const bool wlane = ((l & 33) == 0);
    const bool st = (wid == 0) && (l < 32);

    float hcp = 0.f;
    float2 xc0, xc1;                 // distance-2 x prefetch
    if (st) {
      xc0 = *(const float2*)(xg + 2 * F_ + 2 * l);
      xc1 = *(const float2*)(xg + 3 * F_ + 2 * l);
    }

    #pragma unroll 4
    for (int p = 0; p <= T_ + 1; ++p) {
      if (p <= T_) {
        const int i = p;
        const float4* sp = (const float4*)&p0s[(i + 3) & 3][0];  // stats0[i-1]
        float4 sa = sp[0], sb = sp[1];
        float ss  = (sa.x + sa.z) + (sb.x + sb.z);
        float s2s = (sa.y + sa.w) + (sb.y + sb.w);
        if (st) {                    // write x[i+2]; issue load of x[i+4]
          x4[(i + 2) & 3][l] = as_u32(pkf16(xc0.x, xc0.y));
          xc0 = xc1;
          int tn = (i + 4 < T_) ? (i + 4) : (T_ - 1);
          xc1 = *(const float2*)(xg + tn * F_ + 2 * l);
        }
        const uint32_t* ub = h0p[(i + 1) & 1];     // hc0[i-1]
        const uint32_t* xb = x4[i & 3];            // x[i]
        f32x4 aH0 = {0.f,0.f,0.f,0.f}, aH1 = {0.f,0.f,0.f,0.f};
        f32x4 aX0 = {0.f,0.f,0.f,0.f}, aX1 = {0.f,0.f,0.f,0.f};
        f32x4 aT0 = {0.f,0.f,0.f,0.f}, aT1 = {0.f,0.f,0.f,0.f};
        #pragma unroll
        for (int m = 0; m < 4; ++m) {
          h8 af = ldfrag(ub + m * 16 + g4);
          aH0 = MFMA16(af, wh0[m], aH0);
          aH1 = MFMA16(af, wh1[m], aH1);
        }
        #pragma unroll
        for (int m = 0; m < 2; ++m) {
          h8 xf = ldfrag(xb + m * 16 + g4);
          aX0 = MFMA16(xf, wx0[m], aX0);
          aX1 = MFMA16(xf, wx1[m], aX1);
          aT0 = MFMA16(xf, wt0[m], aT0);
          aT1 = MFMA16(xf, wt1[m], aT1);
        }
        float aH = selT1 ? aH1[0] : aH0[0];
        float aX = selT1 ? aX1[0] : aX0[0];
        float aT = selT1 ? aT1[0] : aT0[0];
        float mu = ss * (1.f / 128.f);
        float m2 = s2s * (1.f / 128.f);
        float rstd = rsq_fast(m2 - mu * mu + EPS_);
        float fl = (i > 0) ? 1.f : 0.f;
        float sc = fl * rstd;
        float pa = fmaf(sc, aH, fmaf(-sc * mu, cg, fl * cb)) + aX + bhx;
        float pt = aT + btr;
        float f   = tanh_fast(pa);
        float tau = taub + softplus_fast(pt);
        float hold = fl * fmaf((hcp - mu) * rstd, gr, ber);   // hn0[i-1][ct]
        float hc  = fmaf(f - hold, __builtin_amdgcn_rcpf(tau), hold);
        // publish hn0[i-1] (for B); slot (i-1)&3
        float hn2 = __shfl_xor(hold, 1);
        if (wlane) hn0p[(i + 3) & 3][widx] = as_u32(pkf16(hold, hn2));
        // publish raw hc0[i] (for own next step)
        float hc2 = __shfl_xor(hc, 1);
        if (wlane) h0p[i & 1][widx] = as_u32(pkf16(hc, hc2));
        // publish stats0[i] (per-wave slot, no atomics)
        float v = (l & 32) ? hc * hc : hc;
        v = red16(v); v += __shfl_xor(v, 16);
        float v2 = __shfl_down(v, 32);             // lane0: (s, s2)
        if (l == 0) p0s[i & 3][wid] = make_float2(v, v2);
        hcp = hc;
      }
      wg_barrier();
    }
  } else {
    // ========== group B: layer 1, step j = p-2; cols (wid-4)*32 .. +31 ==========
    const int c0 = (wid - 4) * 32 + (l & 15);
    const int ct = (wid - 4) * 32 + (l & 31);
    h8 vh0[4], vh1[4], vx0[4], vx1[4], vt0[4], vt1[4];
    float cAg, cAb;
    {
      float d1 = 0.f, d2 = 0.f, e1 = 0.f, e2 = 0.f;
      const float* p0 = Wh1 + c0 * H_ + g8;
      const float* p1 = Wh1 + (c0 + 16) * H_ + g8;
      const float* q0 = Wx1 + c0 * H_ + g8;
      const float* q1 = Wx1 + (c0 + 16) * H_ + g8;
      const float* r0 = Wt1 + c0 * H_ + g8;
      const float* r1 = Wt1 + (c0 + 16) * H_ + g8;
      #pragma unroll
      for (int m = 0; m < 4; ++m) {
        vh0[m] = packfrag_g(p0 + 32 * m, g1 + g8 + 32 * m, be1 + g8 + 32 * m, d1, d2);
        vh1[m] = packfrag_g(p1 + 32 * m, g1 + g8 + 32 * m, be1 + g8 + 32 * m, e1, e2);
        vx0[m] = packfrag(q0 + 32 * m); vx1[m] = packfrag(q1 + 32 * m);  // plain:
        vt0[m] = packfrag(r0 + 32 * m); vt1[m] = packfrag(r1 + 32 * m);  // input is hn0
      }
      d1 += __shfl_xor(d1, 16); d1 += __shfl_xor(d1, 32);
      d2 += __shfl_xor(d2, 16); d2 += __shfl_xor(d2, 32);
      e1 += __shfl_xor(e1, 16); e1 += __shfl_xor(e1, 32);
      e2 += __shfl_xor(e2, 16); e2 += __shfl_xor(e2, 32);
      cAg = selT1 ? e1 : d1; cAb = selT1 ? e2 : d2;
    }
    const float bhx = bh1[ct] + bx1[ct];
    const float btr = bt1[ct], taub = tau1[ct], gr = g1[ct], ber = be1[ct];
    const int  widx = (wid - 4) * 16 + ((l & 31) >> 1);
    const bool wlane = ((l & 33) == 0);
    const int  bw = wid - 4;

    float hcp = 0.f;
    #pragma unroll 2
    for (int p = 0; p <= T_ + 1; ++p) {
      if (p >= 2) {
        const int j = p - 2;
        const float4* sp = (const float4*)&p1s[(j + 3) & 3][0];  // stats1[j-1]
        float4 sa = sp[0], sb = sp[1];
        float ss1 = (sa.x + sa.z) + (sb.x + sb.z);
        float s21 = (sa.y + sa.w) + (sb.y + sb.w);
        const uint32_t* u1b = h1p[(j + 1) & 1];    // hc1[j-1]
        const uint32_t* hnb = hn0p[j & 3];         // hn0[j] (published by A)
        f32x4 aA0 = {0.f,0.f,0.f,0.f}, aA1 = {0.f,0.f,0.f,0.f};
        f32x4 aB0 = {0.f,0.f,0.f,0.f}, aB1 = {0.f,0.f,0.f,0.f};
        f32x4 aT0 = {0.f,0.f,0.f,0.f}, aT1 = {0.f,0.f,0.f,0.f};
        #pragma unroll
        for (int m = 0; m < 4; ++m) {
          h8 af = ldfrag(u1b + m * 16 + g4);
          aA0 = MFMA16(af, vh0[m], aA0);
          aA1 = MFMA16(af, vh1[m], aA1);
        }
        #pragma unroll
        for (int m = 0; m < 4; ++m) {
          h8 f0 = ldfrag(hnb + m * 16 + g4);
          aB0 = MFMA16(f0, vx0[m], aB0);
          aB1 = MFMA16(f0, vx1[m], aB1);
          aT0 = MFMA16(f0, vt0[m], aT0);
          aT1 = MFMA16(f0, vt1[m], aT1);
        }
        float aA = selT1 ? aA1[0] : aA0[0];
        float aB = selT1 ? aB1[0] : aB0[0];
        float aT = selT1 ? aT1[0] : aT0[0];
        float mu1 = ss1 * (1.f / 128.f);
        float m21 = s21 * (1.f / 128.f);
        float rstd1 = rsq_fast(m21 - mu1 * mu1 + EPS_);
        float fl1 = (j > 0) ? 1.f : 0.f;
        float sc1 = fl1 * rstd1;
        float pa = fmaf(sc1, aA, fmaf(-sc1 * mu1, cAg, fl1 * cAb)) + aB + bhx;
        float pt = aT + btr;
        float f   = tanh_fast(pa);
        float tau = taub + softplus_fast(pt);
        float hold = fl1 * fmaf((hcp - mu1) * rstd1, gr, ber);  // hn1[j-1][ct]
        float hc  = fmaf(f - hold, __builtin_amdgcn_rcpf(tau), hold);
        float hc2 = __shfl_xor(hc, 1);
        if (wlane) h1p[j & 1][widx] = as_u32(pkf16(hc, hc2));
        float v = (l & 32) ? hc * hc : hc;
        v = red16(v); v += __shfl_xor(v, 16);
        float v2 = __shfl_down(v, 32);
        if (l == 0) p1s[j & 3][bw] = make_float2(v, v2);
        hcp = hc;
      }
      wg_barrier();
    }
    // epilogue: hn1[T-1] = LN(hc1[T-1]) from stats1[T-1] (slot 3)
    {
      const float4* sp = (const float4*)&p1s[(T_ - 1) & 3][0];
      float4 sa = sp[0], sb = sp[1];
      float ss1 = (sa.x + sa.z) + (sb.x + sb.z);
      float s21 = (sa.y + sa.w) + (sb.y + sb.w);
      float mu1 = ss1 * (1.f / 128.f);
      float m21 = s21 * (1.f / 128.f);
      float rstd1 = rsq_fast(m21 - mu1 * mu1 + EPS_);
      float hn = fmaf((hcp - mu1) * rstd1, gr, ber);
      if (l < 32) out[b * H_ + ct] = hn;
    }
  }
}

extern "C" void kernel_launch(void* const* d_in, const int* in_sizes, int n_in,
                              void* d_out, int out_size, void* d_ws, size_t ws_size,
                              hipStream_t stream) {
  const float* x    = (const float*)d_in[0];
  const float* Wh0  = (const float*)d_in[1];
  const float* bh0  = (const float*)d_in[2];
  const float* Wx0  = (const float*)d_in[3];
  const float* bx0  = (const float*)d_in[4];
  const float* Wt0  = (const float*)d_in[5];
  const float* bt0  = (const float*)d_in[6];
  const float* tau0 = (const float*)d_in[7];
  const float* g0   = (const float*)d_in[8];
  const float* be0  = (const float*)d_in[9];
  const float* Wh1  = (const float*)d_in[10];
  const float* bh1  = (const float*)d_in[11];
  const float* Wx1  = (const float*)d_in[12];
  const float* bx1  = (const float*)d_in[13];
  const float* Wt1  = (const float*)d_in[14];
  const float* bt1  = (const float*)d_in[15];
  const float* tau1 = (const float*)d_in[16];
  const float* g1   = (const float*)d_in[17];
  const float* be1  = (const float*)d_in[18];
  float* out        = (float*)d_out;

  ltc_scan<<<B_, NT_, 0, stream>>>(x, Wh0, bh0, Wx0, bx0, Wt0, bt0, tau0, g0, be0,
                                   Wh1, bh1, Wx1, bx1, Wt1, bt1, tau1, g1, be1, out);
}

// Round 13
// 834.476 us; speedup vs baseline: 3.2715x; 1.0495x over previous
//
#include <hip/hip_runtime.h>
#include <stdint.h>

// LTC encoder B=256,T=1024,F=64,H=128. One WG per batch row, NT=512.
// R21 = R20 + A's x-GEMV software-pipelined one phase ahead.
// R20 post-mortem: 875us, MFMA 34.6 + VALU 40.5 = 75%; remaining 25% is
// in-phase dependency chain (ds_read -> 4-deep Wh MFMA -> scalar tail).
// x[i] is in LDS one full phase early, so the Wx0/Wt0 MFMAs for step i+1
// run at the BOTTOM of phase i (after publishes): they execute on the
// matrix pipe in parallel with the scalar tail + barrier wait, and merge
// to 2 carried scalars (biases folded) -> off the pa-chain entirely.
// A's Wh accumulation also split 2x4-deep -> 4x2-deep chains.
// B untouched (attribution: if neutral, B is the phase-critical wave).
// Base (verified R20): A publishes hn0, B runs j=p-2 consuming hn0 direct
// (no LN-distribution on B's input paths); per-wave-slot stats; lgkm-only
// wg_barrier; 8 waves, 32 cols/wave via two 16x16x32 tiles; gamma-folded
// self-recurrence weights.

#define B_ 256
#define T_ 1024
#define F_ 64
#define H_ 128
#define EPS_ 1e-5f
#define NT_ 512

typedef _Float16 h2 __attribute__((ext_vector_type(2)));
typedef _Float16 h8 __attribute__((ext_vector_type(8)));
typedef float f32x4 __attribute__((ext_vector_type(4)));
typedef __fp16  f16v2 __attribute__((ext_vector_type(2)));

__device__ __forceinline__ h2 pkf16(float a, float b) {
  union { f16v2 f; h2 h; } c;
  c.f = __builtin_amdgcn_cvt_pkrtz(a, b);
  return c.h;
}
__device__ __forceinline__ uint32_t as_u32(h2 h) { union { h2 h; uint32_t u; } c; c.h = h; return c.u; }

// workgroup barrier WITHOUT vmcnt drain: LDS ops complete (lgkmcnt),
// global loads stay in flight across the barrier.
__device__ __forceinline__ void wg_barrier() {
  asm volatile("s_waitcnt lgkmcnt(0)\n\ts_barrier" ::: "memory");
}

#if __has_builtin(__builtin_amdgcn_rsqf)
__device__ __forceinline__ float rsq_fast(float x) { return __builtin_amdgcn_rsqf(x); }
#else
__device__ __forceinline__ float rsq_fast(float x) { return rsqrtf(x); }
#endif

// 16-lane sum via DPP row_ror (every lane of each 16-row gets the row sum).
#if __has_builtin(__builtin_amdgcn_update_dpp)
template <int CTRL>
__device__ __forceinline__ float dpp_add(float v) {
  union { float f; int i; } a, b;
  a.f = v;
  b.i = __builtin_amdgcn_update_dpp(0, a.i, CTRL, 0xf, 0xf, true);
  return v + b.f;
}
__device__ __forceinline__ float red16(float v) {
  v = dpp_add<0x128>(v);   // row_ror:8
  v = dpp_add<0x124>(v);   // row_ror:4
  v = dpp_add<0x122>(v);   // row_ror:2
  v = dpp_add<0x121>(v);   // row_ror:1
  return v;
}
#else
__device__ __forceinline__ float red16(float v) {
  v += __shfl_xor(v, 1); v += __shfl_xor(v, 2);
  v += __shfl_xor(v, 4); v += __shfl_xor(v, 8);
  return v;
}
#endif

// pack 8 consecutive fp32 weights into one MFMA half-fragment (4 VGPRs)
__device__ __forceinline__ h8 packfrag(const float* p) {
  float4 a = *(const float4*)p;
  float4 b = *(const float4*)(p + 4);
  union { h2 h[4]; h8 v; } c;
  c.h[0] = pkf16(a.x, a.y); c.h[1] = pkf16(a.z, a.w);
  c.h[2] = pkf16(b.x, b.y); c.h[3] = pkf16(b.z, b.w);
  return c.v;
}
// load 8 fp32 weights, fold LN-gamma into the k-dim, accumulate Sum(w*g)
// (= sum of folded values) and Sum(w*be); return folded frag as f16.
__device__ __forceinline__ h8 packfrag_g(const float* w, const float* gv, const float* bv,
                                         float& dg, float& dbe) {
  float4 a = *(const float4*)w;
  float4 b = *(const float4*)(w + 4);
  float4 ga = *(const float4*)gv;
  float4 gb = *(const float4*)(gv + 4);
  float4 ba = *(const float4*)bv;
  float4 bb = *(const float4*)(bv + 4);
  float w0 = a.x*ga.x, w1 = a.y*ga.y, w2 = a.z*ga.z, w3 = a.w*ga.w;
  float w4 = b.x*gb.x, w5 = b.y*gb.y, w6 = b.z*gb.z, w7 = b.w*gb.w;
  dg  += (w0 + w1) + (w2 + w3) + (w4 + w5) + (w6 + w7);
  dbe += a.x*ba.x + a.y*ba.y + a.z*ba.z + a.w*ba.w
       + b.x*bb.x + b.y*bb.y + b.z*bb.z + b.w*bb.w;
  union { h2 h[4]; h8 v; } c;
  c.h[0] = pkf16(w0, w1); c.h[1] = pkf16(w2, w3);
  c.h[2] = pkf16(w4, w5); c.h[3] = pkf16(w6, w7);
  return c.v;
}
// broadcast A-fragment from packed-f16 LDS (16B per lane-group, conflict-free)
__device__ __forceinline__ h8 ldfrag(const uint32_t* p) {
  union { uint4 u; h8 v; } c;
  c.u = *(const uint4*)p;
  return c.v;
}

__device__ __forceinline__ float tanh_fast(float a) {
  float aa = fabsf(a);
  float e  = __expf(2.f * aa);
  float th = 1.f - 2.f * __builtin_amdgcn_rcpf(e + 1.f);
  return copysignf(th, a);
}
__device__ __forceinline__ float softplus_fast(float x) {
  return (x > 20.f) ? x : __logf(1.f + __expf(x));
}

#define MFMA16(A_, B_, C_) __builtin_amdgcn_mfma_f32_16x16x32_f16(A_, B_, C_, 0, 0, 0)

__global__ void __attribute__((amdgpu_flat_work_group_size(NT_, NT_)))
                __attribute__((amdgpu_waves_per_eu(2, 2)))
ltc_scan(
    const float* __restrict__ x,
    const float* __restrict__ Wh0, const float* __restrict__ bh0,
    const float* __restrict__ Wx0, const float* __restrict__ bx0,
    const float* __restrict__ Wt0, const float* __restrict__ bt0,
    const float* __restrict__ tau0, const float* __restrict__ g0,
    const float* __restrict__ be0,
    const float* __restrict__ Wh1, const float* __restrict__ bh1,
    const float* __restrict__ Wx1, const float* __restrict__ bx1,
    const float* __restrict__ Wt1, const float* __restrict__ bt1,
    const float* __restrict__ tau1, const float* __restrict__ g1,
    const float* __restrict__ be1,
    float* __restrict__ out)
{
  __shared__ __align__(16) uint32_t h0p[2][64];   // hc0 raw, A-only dbuf
  __shared__ __align__(16) uint32_t h1p[2][64];   // hc1 raw, B-only dbuf
  __shared__ __align__(16) uint32_t hn0p[4][64];  // hn0[i] = LN(hc0[i]), 4-ring
  __shared__ __align__(16) uint32_t x4[4][32];    // x[t] packed f16, 4-ring
  __shared__ __align__(16) float2   p0s[4][4];    // L0 stats [slot][wave]{s,s2}
  __shared__ __align__(16) float2   p1s[4][4];    // L1 stats

  const int tid = threadIdx.x;
  const int wid = tid >> 6;
  const int l   = tid & 63;
  const int g4  = (l >> 4) << 2;    // LDS u32 offset of this dup-group's frag
  const int g8  = (l >> 4) << 3;    // k offset (floats) of this dup-group
  const int b   = blockIdx.x;
  const float* xg = x + (size_t)b * (T_ * F_);
  const bool selT1 = (l & 16) != 0; // lanes 16-31 / 48-63 serve tile 1

  if (tid < 128) { ((uint32_t*)h0p)[tid] = 0u; ((uint32_t*)h1p)[tid] = 0u; }
  if (tid < 32)  { ((float*)p0s)[tid] = 0.f; ((float*)p1s)[tid] = 0.f; }
  if (tid < 32) {                   // stage x[0], x[1]
    float2 a = *(const float2*)(xg + 2 * tid);
    float2 c = *(const float2*)(xg + F_ + 2 * tid);
    x4[0][tid] = as_u32(pkf16(a.x, a.y));
    x4[1][tid] = as_u32(pkf16(c.x, c.y));
  }
  __syncthreads();                  // one full barrier at start (drains init)

  if (wid < 4) {
    // ========== group A: layer 0, step i = p; cols wid*32 .. +31 ==========
    const int c0 = wid * 32 + (l & 15);
    const int ct = wid * 32 + (l & 31);
    h8 wh0[4], wh1[4], wx0[2], wx1[2], wt0[2], wt1[2];
    float cg, cb;
    {
      float dg0 = 0.f, db0 = 0.f, dg1 = 0.f, db1 = 0.f;
      const float* p0 = Wh0 + c0 * H_ + g8;
      const float* p1 = Wh0 + (c0 + 16) * H_ + g8;
      #pragma unroll
      for (int m = 0; m < 4; ++m) {
        wh0[m] = packfrag_g(p0 + 32 * m, g0 + g8 + 32 * m, be0 + g8 + 32 * m, dg0, db0);
        wh1[m] = packfrag_g(p1 + 32 * m, g0 + g8 + 32 * m, be0 + g8 + 32 * m, dg1, db1);
      }
      dg0 += __shfl_xor(dg0, 16); dg0 += __shfl_xor(dg0, 32);
      db0 += __shfl_xor(db0, 16); db0 += __shfl_xor(db0, 32);
      dg1 += __shfl_xor(dg1, 16); dg1 += __shfl_xor(dg1, 32);
      db1 += __shfl_xor(db1, 16); db1 += __shfl_xor(db1, 32);
      cg = selT1 ? dg1 : dg0; cb = selT1 ? db1 : db0;
      const float* q0 = Wx0 + c0 * F_ + g8;
      const float* q1 = Wx0 + (c0 + 16) * F_ + g8;
      const float* r0 = Wt0 + c0 * F_ + g8;
      const float* r1 = Wt0 + (c0 + 16) * F_ + g8;
      #pragma unroll
      for (int m = 0; m < 2; ++m) {
        wx0[m] = packfrag(q0 + 32 * m); wx1[m] = packfrag(q1 + 32 * m);
        wt0[m] = packfrag(r0 + 32 * m); wt1[m] = packfrag(r1 + 32 * m);
      }
    }
    const float bhx = bh0[ct] + bx0[ct];
    const float btr = bt0[ct], taub = tau0[ct], gr = g0[ct], ber = be0[ct];
    const int  widx = wid * 16 + ((l & 31) >> 1);
    const bool wlane = ((l & 33) == 0);
    const bool st = (wid == 0) && (l < 32);

    float hcp = 0.f;
    float2 xc0, xc1;                 // distance-2 x prefetch
    if (st) {
      xc0 = *(const float2*)(xg + 2 * F_ + 2 * l);
      xc1 = *(const float2*)(xg + 3 * F_ + 2 * l);
    }
    // prologue: x-contributions for step 0 (from x4[0], staged at init)
    float xcs, tcs;
    {
      const uint32_t* xb = x4[0];
      f32x4 nX0 = {0.f,0.f,0.f,0.f}, nX1 = {0.f,0.f,0.f,0.f};
      f32x4 nT0 = {0.f,0.f,0.f,0.f}, nT1 = {0.f,0.f,0.f,0.f};
      #pragma unroll
      for (int m = 0; m < 2; ++m) {
        h8 xf = ldfrag(xb + m * 16 + g4);
        nX0 = MFMA16(xf, wx0[m], nX0);
        nX1 = MFMA16(xf, wx1[m], nX1);
        nT0 = MFMA16(xf, wt0[m], nT0);
        nT1 = MFMA16(xf, wt1[m], nT1);
      }
      xcs = (selT1 ? nX1[0] : nX0[0]) + bhx;
      tcs = (selT1 ? nT1[0] : nT0[0]) + btr;
    }

    #pragma unroll 4
    for (int p = 0; p <= T_ + 1; ++p) {
      if (p <= T_) {
        const int i = p;
        const float4* sp = (const float4*)&p0s[(i + 3) & 3][0];  // stats0[i-1]
        float4 sa = sp[0], sb = sp[1];
        float ss  = (sa.x + sa.z) + (sb.x + sb.z);
        float s2s = (sa.y + sa.w) + (sb.y + sb.w);
        if (st) {                    // write x[i+2]; issue load of x[i+4]
          x4[(i + 2) & 3][l] = as_u32(pkf16(xc0.x, xc0.y));
          xc0 = xc1;
          int tn = (i + 4 < T_) ? (i + 4) : (T_ - 1);
          xc1 = *(const float2*)(xg + tn * F_ + 2 * l);
        }
        const uint32_t* ub = h0p[(i + 1) & 1];     // hc0[i-1]
        // Wh chain: 4 independent 2-deep chains (was 2x4-deep)
        f32x4 aH0a = {0.f,0.f,0.f,0.f}, aH0b = {0.f,0.f,0.f,0.f};
        f32x4 aH1a = {0.f,0.f,0.f,0.f}, aH1b = {0.f,0.f,0.f,0.f};
        {
          h8 af0 = ldfrag(ub + g4);
          h8 af1 = ldfrag(ub + 16 + g4);
          h8 af2 = ldfrag(ub + 32 + g4);
          h8 af3 = ldfrag(ub + 48 + g4);
          aH0a = MFMA16(af0, wh0[0], aH0a); aH1a = MFMA16(af0, wh1[0], aH1a);
          aH0b = MFMA16(af1, wh0[1], aH0b); aH1b = MFMA16(af1, wh1[1], aH1b);
          aH0a = MFMA16(af2, wh0[2], aH0a); aH1a = MFMA16(af2, wh1[2], aH1a);
          aH0b = MFMA16(af3, wh0[3], aH0b); aH1b = MFMA16(af3, wh1[3], aH1b);
        }
        float aH = selT1 ? (aH1a[0] + aH1b[0]) : (aH0a[0] + aH0b[0]);
        float mu = ss * (1.f / 128.f);
        float m2 = s2s * (1.f / 128.f);
        float rstd = rsq_fast(m2 - mu * mu + EPS_);
        float fl = (i > 0) ? 1.f : 0.f;
        float sc = fl * rstd;
        float pa = fmaf(sc, aH, fmaf(-sc * mu, cg, fl * cb)) + xcs;  // xcs has bhx
        float pt = tcs;                                              // tcs has btr
        float f   = tanh_fast(pa);
        float tau = taub + softplus_fast(pt);
        float hold = fl * fmaf((hcp - mu) * rstd, gr, ber);   // hn0[i-1][ct]
        float hc  = fmaf(f - hold, __builtin_amdgcn_rcpf(tau), hold);
        // publish hn0[i-1] (for B); slot (i-1)&3
        float hn2 = __shfl_xor(hold, 1);
        if (wlane) hn0p[(i + 3) & 3][widx] = as_u32(pkf16(hold, hn2));
        // publish raw hc0[i] (for own next step)
        float hc2 = __shfl_xor(hc, 1);
        if (wlane) h0p[i & 1][widx] = as_u32(pkf16(hc, hc2));
        // publish stats0[i] (per-wave slot)
        float v = (l & 32) ? hc * hc : hc;
        v = red16(v); v += __shfl_xor(v, 16);
        float v2 = __shfl_down(v, 32);             // lane0: (s, s2)
        if (l == 0) p0s[i & 3][wid] = make_float2(v, v2);
        hcp = hc;
        // pipelined x-GEMV for step i+1: x[i+1] already in LDS; these
        // MFMAs overlap the tail + barrier wait (matrix pipe vs VALU).
        {
          const uint32_t* xb = x4[(i + 1) & 3];
          f32x4 nX0 = {0.f,0.f,0.f,0.f}, nX1 = {0.f,0.f,0.f,0.f};
          f32x4 nT0 = {0.f,0.f,0.f,0.f}, nT1 = {0.f,0.f,0.f,0.f};
          #pragma unroll
          for (int m = 0; m < 2; ++m) {
            h8 xf = ldfrag(xb + m * 16 + g4);
            nX0 = MFMA16(xf, wx0[m], nX0);
            nX1 = MFMA16(xf, wx1[m], nX1);
            nT0 = MFMA16(xf, wt0[m], nT0);
            nT1 = MFMA16(xf, wt1[m], nT1);
          }
          xcs = (selT1 ? nX1[0] : nX0[0]) + bhx;
          tcs = (selT1 ? nT1[0] : nT0[0]) + btr;
        }
      }
      wg_barrier();
    }
  } else {
    // ========== group B: layer 1, step j = p-2; cols (wid-4)*32 .. +31 ==========
    const int c0 = (wid - 4) * 32 + (l & 15);
    const int ct = (wid - 4) * 32 + (l & 31);
    h8 vh0[4], vh1[4], vx0[4], vx1[4], vt0[4], vt1[4];
    float cAg, cAb;
    {
      float d1 = 0.f, d2 = 0.f, e1 = 0.f, e2 = 0.f;
      const float* p0 = Wh1 + c0 * H_ + g8;
      const float* p1 = Wh1 + (c0 + 16) * H_ + g8;
      const float* q0 = Wx1 + c0 * H_ + g8;
      const float* q1 = Wx1 + (c0 + 16) * H_ + g8;
      const float* r0 = Wt1 + c0 * H_ + g8;
      const float* r1 = Wt1 + (c0 + 16) * H_ + g8;
      #pragma unroll
      for (int m = 0; m < 4; ++m) {
        vh0[m] = packfrag_g(p0 + 32 * m, g1 + g8 + 32 * m, be1 + g8 + 32 * m, d1, d2);
        vh1[m] = packfrag_g(p1 + 32 * m, g1 + g8 + 32 * m, be1 + g8 + 32 * m, e1, e2);
        vx0[m] = packfrag(q0 + 32 * m); vx1[m] = packfrag(q1 + 32 * m);  // plain:
        vt0[m] = packfrag(r0 + 32 * m); vt1[m] = packfrag(r1 + 32 * m);  // input is hn0
      }
      d1 += __shfl_xor(d1, 16); d1 += __shfl_xor(d1, 32);
      d2 += __shfl_xor(d2, 16); d2 += __shfl_xor(d2, 32);
      e1 += __shfl_xor(e1, 16); e1 += __shfl_xor(e1, 32);
      e2 += __shfl_xor(e2, 16); e2 += __shfl_xor(e2, 32);
      cAg = selT1 ? e1 : d1; cAb = selT1 ? e2 : d2;
    }
    const float bhx = bh1[ct] + bx1[ct];
    const float btr = bt1[ct], taub = tau1[ct], gr = g1[ct], ber = be1[ct];
    const int  widx = (wid - 4) * 16 + ((l & 31) >> 1);
    const bool wlane = ((l & 33) == 0);
    const int  bw = wid - 4;

    float hcp = 0.f;
    #pragma unroll 2
    for (int p = 0; p <= T_ + 1; ++p) {
      if (p >= 2) {
        const int j = p - 2;
        const float4* sp = (const float4*)&p1s[(j + 3) & 3][0];  // stats1[j-1]
        float4 sa = sp[0], sb = sp[1];
        float ss1 = (sa.x + sa.z) + (sb.x + sb.z);
        float s21 = (sa.y + sa.w) + (sb.y + sb.w);
        const uint32_t* u1b = h1p[(j + 1) & 1];    // hc1[j-1]
        const uint32_t* hnb = hn0p[j & 3];         // hn0[j] (published by A)
        f32x4 aA0 = {0.f,0.f,0.f,0.f}, aA1 = {0.f,0.f,0.f,0.f};
        f32x4 aB0 = {0.f,0.f,0.f,0.f}, aB1 = {0.f,0.f,0.f,0.f};
        f32x4 aT0 = {0.f,0.f,0.f,0.f}, aT1 = {0.f,0.f,0.f,0.f};
        #pragma unroll
        for (int m = 0; m < 4; ++m) {
          h8 af = ldfrag(u1b + m * 16 + g4);
          aA0 = MFMA16(af, vh0[m], aA0);
          aA1 = MFMA16(af, vh1[m], aA1);
        }
        #pragma unroll
        for (int m = 0; m < 4; ++m) {
          h8 f0 = ldfrag(hnb + m * 16 + g4);
          aB0 = MFMA16(f0, vx0[m], aB0);
          aB1 = MFMA16(f0, vx1[m], aB1);
          aT0 = MFMA16(f0, vt0[m], aT0);
          aT1 = MFMA16(f0, vt1[m], aT1);
        }
        float aA = selT1 ? aA1[0] : aA0[0];
        float aB = selT1 ? aB1[0] : aB0[0];
        float aT = selT1 ? aT1[0] : aT0[0];
        float mu1 = ss1 * (1.f / 128.f);
        float m21 = s21 * (1.f / 128.f);
        float rstd1 = rsq_fast(m21 - mu1 * mu1 + EPS_);
        float fl1 = (j > 0) ? 1.f : 0.f;
        float sc1 = fl1 * rstd1;
        float pa = fmaf(sc1, aA, fmaf(-sc1 * mu1, cAg, fl1 * cAb)) + aB + bhx;
        float pt = aT + btr;
        float f   = tanh_fast(pa);
        float tau = taub + softplus_fast(pt);
        float hold = fl1 * fmaf((hcp - mu1) * rstd1, gr, ber);  // hn1[j-1][ct]
        float hc  = fmaf(f - hold, __builtin_amdgcn_rcpf(tau), hold);
        float hc2 = __shfl_xor(hc, 1);
        if (wlane) h1p[j & 1][widx] = as_u32(pkf16(hc, hc2));
        float v = (l & 32) ? hc * hc : hc;
        v = red16(v); v += __shfl_xor(v, 16);
        float v2 = __shfl_down(v, 32);
        if (l == 0) p1s[j & 3][bw] = make_float2(v, v2);
        hcp = hc;
      }
      wg_barrier();
    }
    // epilogue: hn1[T-1] = LN(hc1[T-1]) from stats1[T-1] (slot 3)
    {
      const float4* sp = (const float4*)&p1s[(T_ - 1) & 3][0];
      float4 sa = sp[0], sb = sp[1];
      float ss1 = (sa.x + sa.z) + (sb.x + sb.z);
      float s21 = (sa.y + sa.w) + (sb.y + sb.w);
      float mu1 = ss1 * (1.f / 128.f);
      float m21 = s21 * (1.f / 128.f);
      float rstd1 = rsq_fast(m21 - mu1 * mu1 + EPS_);
      float hn = fmaf((hcp - mu1) * rstd1, gr, ber);
      if (l < 32) out[b * H_ + ct] = hn;
    }
  }
}

extern "C" void kernel_launch(void* const* d_in, const int* in_sizes, int n_in,
                              void* d_out, int out_size, void* d_ws, size_t ws_size,
                              hipStream_t stream) {
  const float* x    = (const float*)d_in[0];
  const float* Wh0  = (const float*)d_in[1];
  const float* bh0  = (const float*)d_in[2];
  const float* Wx0  = (const float*)d_in[3];
  const float* bx0  = (const float*)d_in[4];
  const float* Wt0  = (const float*)d_in[5];
  const float* bt0  = (const float*)d_in[6];
  const float* tau0 = (const float*)d_in[7];
  const float* g0   = (const float*)d_in[8];
  const float* be0  = (const float*)d_in[9];
  const float* Wh1  = (const float*)d_in[10];
  const float* bh1  = (const float*)d_in[11];
  const float* Wx1  = (const float*)d_in[12];
  const float* bx1  = (const float*)d_in[13];
  const float* Wt1  = (const float*)d_in[14];
  const float* bt1  = (const float*)d_in[15];
  const float* tau1 = (const float*)d_in[16];
  const float* g1   = (const float*)d_in[17];
  const float* be1  = (const float*)d_in[18];
  float* out        = (float*)d_out;

  ltc_scan<<<B_, NT_, 0, stream>>>(x, Wh0, bh0, Wx0, bx0, Wt0, bt0, tau0, g0, be0,
                                   Wh1, bh1, Wx1, bx1, Wt1, bt1, tau1, g1, be1, out);
}